// Round 8
// baseline (312.209 us; speedup 1.0000x reference)
//
#include <hip/hip_runtime.h>
#include <math.h>

// Problem constants (b=8, n=4096, c=768, h=8, d=96)
#define NB  8
#define SEQ 4096
#define CH  768
#define NH  8
#define HD  96
#define NC3 2304   // 3*CH

typedef _Float16 f16x8 __attribute__((ext_vector_type(8)));
typedef float    f32x4 __attribute__((ext_vector_type(4)));

// ---------------------------------------------------------------------------
// Workspace layout (BYTE offsets). Base = 118,407,168 B (proven). Optional
// XH2 (fp16 x row-major) appended if ws_size >= 168,738,816.
// ---------------------------------------------------------------------------
static const size_t XT_B   = 0;           // fp16 x^T [b][c][n]; dies after G
static const size_t UT_B   = 0;           // overlays XT
static const size_t ATT_B  = 28311552;
static const size_t MT_B   = 29491200;
static const size_t PT_B   = 38928384;
static const size_t GP_B   = 50331648;    // G partials; dies after reduce
static const size_t XH_B   = 50331648;    // fallback XH (fills after reduce)
static const size_t WH_B   = 100663296;
static const size_t WT_B   = 104202240;
static const size_t WPT_B  = 107741184;
static const size_t G_B    = 108920832;
static const size_t INV_B  = 118358016;
static const size_t XH2_B  = 118407168;   // fast-path XH (needs big ws)
static const size_t XH_BYTES = (size_t)NB * SEQ * CH * 2;   // 50,331,648

// ---------------------------------------------------------------------------
// async global->LDS, 16 B per lane (wave-uniform LDS base + lane*16)
// ---------------------------------------------------------------------------
__device__ __forceinline__ void gload16(const void* g, void* l) {
  __builtin_amdgcn_global_load_lds(
      (const __attribute__((address_space(1))) void*)g,
      (__attribute__((address_space(3))) void*)l, 16, 0, 0);
}

// ---------------------------------------------------------------------------
// Elementwise fp32 -> fp16 convert
// ---------------------------------------------------------------------------
__global__ void cvt_f16_kernel(const float* __restrict__ in,
                               _Float16* __restrict__ out, int n4) {
  int i = blockIdx.x * blockDim.x + threadIdx.x;
  if (i < n4) {
    float4 v = *(const float4*)(in + (size_t)i * 4);
    _Float16* o = out + (size_t)i * 4;
    o[0] = (_Float16)v.x; o[1] = (_Float16)v.y;
    o[2] = (_Float16)v.z; o[3] = (_Float16)v.w;
  }
}

// ---------------------------------------------------------------------------
// Tiled transpose+convert: fp32 [R][C] -> fp16 [C][R]; optional fp16 [R][C].
// ---------------------------------------------------------------------------
__global__ void transpose_cvt_kernel(const float* __restrict__ in,
                                     _Float16* __restrict__ outT,
                                     _Float16* __restrict__ outH,
                                     int R, int C, long sIn, long sOut) {
  __shared__ float t[32][33];
  const int b = blockIdx.z;
  const int c0 = blockIdx.x * 32, r0 = blockIdx.y * 32;
  const int tx = threadIdx.x & 31, ty = threadIdx.x >> 5;
  const float* ib = in + (size_t)b * sIn;
  _Float16* ob = outT + (size_t)b * sOut;
#pragma unroll
  for (int k = 0; k < 4; ++k) {
    float v = ib[(size_t)(r0 + ty + 8 * k) * C + c0 + tx];
    t[ty + 8 * k][tx] = v;
    if (outH)
      outH[(size_t)b * sOut + (size_t)(r0 + ty + 8 * k) * C + c0 + tx] = (_Float16)v;
  }
  __syncthreads();
#pragma unroll
  for (int k = 0; k < 4; ++k)
    ob[(size_t)(c0 + ty + 8 * k) * R + r0 + tx] = (_Float16)t[tx][ty + 8 * k];
}

// ---------------------------------------------------------------------------
// 256x256 8-wave MFMA GEMM, BK=64, 4 MFMA phases per K-tile.
// T4-fixed: ALL 8 next-tile global_load_lds issue at iteration START (writes
// nxt while reads hit cur), so the boundary vmcnt(0) waits on loads that have
// been in flight for ~4 phases (near-free). s_setprio around MFMA clusters.
// 3-bit XOR slot swizzle on both sides of the gload involution.
// 1D grid + XCD chunk swizzle (nwg%8==0). TRI: upper-tri gx*gx tiling.
// Requires M%256==0, N%256==0, K%64==0.
// ---------------------------------------------------------------------------
template<bool FP16OUT, bool BIAS, bool TRI>
__global__ __launch_bounds__(512) void gemm_bt_256(
    const _Float16* __restrict__ Ap, const _Float16* __restrict__ Bp,
    const float* __restrict__ bias, void* __restrict__ Cp,
    int K, int lda, int ldb, int ldc,
    long sA, long sB, long sC, int zdiv, long aCS, long bCS, long cCS,
    int gx, int gy) {
  __shared__ __align__(16) _Float16 lds[2][2][256 * 64];   // 128 KiB

  const int nwg = gridDim.x;
  const int lid = blockIdx.x;
  const int wg = (lid & 7) * (nwg >> 3) + (lid >> 3);
  int bx, by, z;
  if constexpr (TRI) {
    const int ntri = gx * (gx + 1) / 2;
    int tt = wg % ntri; z = wg / ntri;
    int ti = 0, rem = tt;
    while (rem >= gx - ti) { rem -= gx - ti; ++ti; }
    by = ti; bx = ti + rem;
  } else {
    bx = wg % gx; int r2 = wg / gx; by = r2 % gy; z = r2 / gy;
  }
  const int bat = z % zdiv, chk = z / zdiv;
  const _Float16* A = Ap + (size_t)bat * sA + (size_t)chk * aCS;
  const _Float16* B = Bp + (size_t)bat * sB + (size_t)chk * bCS;
  const size_t cOff = (size_t)bat * sC + (size_t)chk * cCS;

  const int row0 = by * 256, col0 = bx * 256;
  const int tid = threadIdx.x;
  const int l = tid & 63, w = tid >> 6;      // 8 waves
  const int lo = l & 15, hi = l >> 4;
  const int wr = w >> 2, wc = w & 3;         // 2 x 4 wave grid -> 128x64/wave

  const int srow = l >> 3;                   // staging: row within 8-row call
  const int sslot = l & 7;                   // 16B slot within 128B row

  f32x4 acc[8][4];
#pragma unroll
  for (int i = 0; i < 8; ++i)
#pragma unroll
    for (int j = 0; j < 4; ++j)
      acc[i][j] = (f32x4){0.f, 0.f, 0.f, 0.f};

  auto STAGE_A = [&](int buf, int k0, int c) {
    const int r = 32 * w + 8 * c + srow;
    const int ck = sslot ^ (r & 7);
    gload16(A + (size_t)(row0 + r) * lda + k0 + 8 * ck,
            &lds[buf][0][(32 * w + 8 * c) * 64]);
  };
  auto STAGE_B = [&](int buf, int k0, int c) {
    const int r = 32 * w + 8 * c + srow;
    const int ck = sslot ^ (r & 7);
    gload16(B + (size_t)(col0 + r) * ldb + k0 + 8 * ck,
            &lds[buf][1][(32 * w + 8 * c) * 64]);
  };
  auto LDA_f = [&](int buf, int mi, int kk) -> f16x8 {
    const int R = 128 * wr + 16 * mi + lo;
    const int sl = (kk * 4 + hi) ^ (R & 7);
    return *(const f16x8*)&lds[buf][0][R * 64 + sl * 8];
  };
  auto LDB_f = [&](int buf, int ni, int kk) -> f16x8 {
    const int R = 64 * wc + 16 * ni + lo;
    const int sl = (kk * 4 + hi) ^ (R & 7);
    return *(const f16x8*)&lds[buf][1][R * 64 + sl * 8];
  };

  // prologue: fully stage K-tile 0
#pragma unroll
  for (int c = 0; c < 4; ++c) STAGE_A(0, 0, c);
#pragma unroll
  for (int c = 0; c < 4; ++c) STAGE_B(0, 0, c);
  asm volatile("s_waitcnt vmcnt(0)" ::: "memory");
  __builtin_amdgcn_s_barrier();

  const int nt = K / 64;
  int cur = 0;
  f16x8 a[4][2], b0[2][2], b1[2][2];

  for (int t = 0; t < nt; ++t) {
    const int nx = cur ^ 1;
    const bool pre = (t + 1 < nt);
    const int k1 = 64 * (t + 1);

    // ---- issue ALL next-tile stages up front: full-iteration latency hide.
    //      Writes lds[nx]; all reads this iteration hit lds[cur]. ----
    if (pre) {
#pragma unroll
      for (int c = 0; c < 4; ++c) STAGE_A(nx, k1, c);
#pragma unroll
      for (int c = 0; c < 4; ++c) STAGE_B(nx, k1, c);
    }

    // ---- phase 1: read a-half0 + b-half0, MFMA quadrant (0,0) ----
#pragma unroll
    for (int mi = 0; mi < 4; ++mi) {
      a[mi][0] = LDA_f(cur, mi, 0); a[mi][1] = LDA_f(cur, mi, 1);
    }
#pragma unroll
    for (int ni = 0; ni < 2; ++ni) {
      b0[ni][0] = LDB_f(cur, ni, 0); b0[ni][1] = LDB_f(cur, ni, 1);
    }
    __builtin_amdgcn_s_barrier();
    __builtin_amdgcn_s_setprio(1);
#pragma unroll
    for (int mi = 0; mi < 4; ++mi)
#pragma unroll
      for (int ni = 0; ni < 2; ++ni)
#pragma unroll
        for (int kk = 0; kk < 2; ++kk)
          acc[mi][ni] = __builtin_amdgcn_mfma_f32_16x16x32_f16(
              a[mi][kk], b0[ni][kk], acc[mi][ni], 0, 0, 0);
    __builtin_amdgcn_s_setprio(0);
    __builtin_amdgcn_s_barrier();

    // ---- phase 2: read b-half1, MFMA quadrant (0,1) ----
#pragma unroll
    for (int ni = 0; ni < 2; ++ni) {
      b1[ni][0] = LDB_f(cur, ni + 2, 0); b1[ni][1] = LDB_f(cur, ni + 2, 1);
    }
    __builtin_amdgcn_s_barrier();
    __builtin_amdgcn_s_setprio(1);
#pragma unroll
    for (int mi = 0; mi < 4; ++mi)
#pragma unroll
      for (int ni = 0; ni < 2; ++ni)
#pragma unroll
        for (int kk = 0; kk < 2; ++kk)
          acc[mi][ni + 2] = __builtin_amdgcn_mfma_f32_16x16x32_f16(
              a[mi][kk], b1[ni][kk], acc[mi][ni + 2], 0, 0, 0);
    __builtin_amdgcn_s_setprio(0);
    __builtin_amdgcn_s_barrier();

    // ---- phase 3: read a-half1, MFMA quadrant (1,0) ----
#pragma unroll
    for (int mi = 0; mi < 4; ++mi) {
      a[mi][0] = LDA_f(cur, mi + 4, 0); a[mi][1] = LDA_f(cur, mi + 4, 1);
    }
    __builtin_amdgcn_s_barrier();
    __builtin_amdgcn_s_setprio(1);
#pragma unroll
    for (int mi = 0; mi < 4; ++mi)
#pragma unroll
      for (int ni = 0; ni < 2; ++ni)
#pragma unroll
        for (int kk = 0; kk < 2; ++kk)
          acc[mi + 4][ni] = __builtin_amdgcn_mfma_f32_16x16x32_f16(
              a[mi][kk], b0[ni][kk], acc[mi + 4][ni], 0, 0, 0);
    __builtin_amdgcn_s_setprio(0);
    __builtin_amdgcn_s_barrier();

    // ---- phase 4: MFMA quadrant (1,1), then boundary sync ----
    __builtin_amdgcn_s_setprio(1);
#pragma unroll
    for (int mi = 0; mi < 4; ++mi)
#pragma unroll
      for (int ni = 0; ni < 2; ++ni)
#pragma unroll
        for (int kk = 0; kk < 2; ++kk)
          acc[mi + 4][ni + 2] = __builtin_amdgcn_mfma_f32_16x16x32_f16(
              a[mi][kk], b1[ni][kk], acc[mi + 4][ni + 2], 0, 0, 0);
    __builtin_amdgcn_s_setprio(0);
    asm volatile("s_waitcnt vmcnt(0)" ::: "memory");   // nxt staged (loads ~4 phases old)
    __builtin_amdgcn_s_barrier();                      // visible to all waves
    cur = nx;
  }

  // epilogue: D col = lane&15, row = 4*(lane>>4)+reg
#pragma unroll
  for (int ni = 0; ni < 4; ++ni) {
    const int col = col0 + 64 * wc + 16 * ni + lo;
    float bv = 0.f;
    if constexpr (BIAS) bv = bias[col];
#pragma unroll
    for (int mi = 0; mi < 8; ++mi) {
      const int rowb = row0 + 128 * wr + 16 * mi + 4 * hi;
#pragma unroll
      for (int r = 0; r < 4; ++r) {
        float v = acc[mi][ni][r] + bv;
        if constexpr (FP16OUT)
          ((_Float16*)Cp)[cOff + (size_t)(rowb + r) * ldc + col] = (_Float16)v;
        else
          ((float*)Cp)[cOff + (size_t)(rowb + r) * ldc + col] = v;
      }
    }
  }
}

// ---------------------------------------------------------------------------
// 128x128 4-wave 2-phase GEMM (proven) — U and Pt GEMMs.
// ---------------------------------------------------------------------------
template<bool FP16OUT, bool BIAS>
__global__ __launch_bounds__(256) void gemm_bt_128(
    const _Float16* __restrict__ Ap, const _Float16* __restrict__ Bp,
    const float* __restrict__ bias, void* __restrict__ Cp,
    int K, int lda, int ldb, int ldc,
    long sA, long sB, long sC, int zdiv, long aCS, long bCS, long cCS,
    int gx, int gy) {
  __shared__ __align__(16) _Float16 ldsA[2][128 * 32];
  __shared__ __align__(16) _Float16 ldsB[2][128 * 32];

  const int nwg = gridDim.x;
  const int lid = blockIdx.x;
  const int wg = (lid & 7) * (nwg >> 3) + (lid >> 3);
  int bx = wg % gx; int r2 = wg / gx; int by = r2 % gy; int z = r2 / gy;
  const int bat = z % zdiv, chk = z / zdiv;
  const _Float16* A = Ap + (size_t)bat * sA + (size_t)chk * aCS;
  const _Float16* B = Bp + (size_t)bat * sB + (size_t)chk * bCS;
  const size_t cOff = (size_t)bat * sC + (size_t)chk * cCS;

  const int row0 = by * 128, col0 = bx * 128;
  const int tid = threadIdx.x;
  const int l = tid & 63, w = tid >> 6;
  const int lo = l & 15, hi = l >> 4;
  const int wr = w >> 1, wc = w & 1;
  const int rw = 32 * w;
  const int lr = l >> 2;
  const int ls = l & 3;

  f32x4 acc[4][4];
#pragma unroll
  for (int i = 0; i < 4; ++i)
#pragma unroll
    for (int j = 0; j < 4; ++j)
      acc[i][j] = (f32x4){0.f, 0.f, 0.f, 0.f};

  auto STAGE = [&](int hb, int k0) {
#pragma unroll
    for (int q = 0; q < 2; ++q) {
      const int r = rw + 16 * q + lr;
      const int ck = ls ^ ((r >> 1) & 3);
      gload16(A + (size_t)(row0 + r) * lda + k0 + 8 * ck,
              &ldsA[hb][(rw + 16 * q) * 32]);
      gload16(B + (size_t)(col0 + r) * ldb + k0 + 8 * ck,
              &ldsB[hb][(rw + 16 * q) * 32]);
    }
  };

  STAGE(0, 0);
  const int nt = K / 32;
  int cur = 0;
  for (int t = 0; t < nt; ++t) {
    if (t + 1 < nt) {
      STAGE(cur ^ 1, 32 * (t + 1));
      asm volatile("s_waitcnt vmcnt(4)" ::: "memory");
    } else {
      asm volatile("s_waitcnt vmcnt(0)" ::: "memory");
    }
    __builtin_amdgcn_s_barrier();

    f16x8 a[4], b[4];
#pragma unroll
    for (int mi = 0; mi < 4; ++mi) {
      int Ra = 64 * wr + 16 * mi + lo;
      a[mi] = *(const f16x8*)&ldsA[cur][Ra * 32 + (hi ^ ((Ra >> 1) & 3)) * 8];
    }
#pragma unroll
    for (int ni = 0; ni < 4; ++ni) {
      int Rb = 64 * wc + 16 * ni + lo;
      b[ni] = *(const f16x8*)&ldsB[cur][Rb * 32 + (hi ^ ((Rb >> 1) & 3)) * 8];
    }
#pragma unroll
    for (int mi = 0; mi < 4; ++mi)
#pragma unroll
      for (int ni = 0; ni < 4; ++ni)
        acc[mi][ni] = __builtin_amdgcn_mfma_f32_16x16x32_f16(
            a[mi], b[ni], acc[mi][ni], 0, 0, 0);

    __builtin_amdgcn_s_barrier();
    cur ^= 1;
  }

#pragma unroll
  for (int ni = 0; ni < 4; ++ni) {
    const int col = col0 + 64 * wc + 16 * ni + lo;
    float bv = 0.f;
    if constexpr (BIAS) bv = bias[col];
#pragma unroll
    for (int mi = 0; mi < 4; ++mi) {
      const int rowb = row0 + 64 * wr + 16 * mi + 4 * hi;
#pragma unroll
      for (int r = 0; r < 4; ++r) {
        float v = acc[mi][ni][r] + bv;
        if constexpr (FP16OUT)
          ((_Float16*)Cp)[cOff + (size_t)(rowb + r) * ldc + col] = (_Float16)v;
        else
          ((float*)Cp)[cOff + (size_t)(rowb + r) * ldc + col] = v;
      }
    }
  }
}

// ---------------------------------------------------------------------------
// Reduce 4 split-K chunks of the 6 upper-tri 256-tiles and mirror to full G.
// grid (6, 8), block 256.
// ---------------------------------------------------------------------------
__global__ void reduce_mirror_kernel(const _Float16* __restrict__ GP,
                                     _Float16* __restrict__ G) {
  const int t = blockIdx.x, b = blockIdx.y;
  int ti = 0, rem = t;
  while (rem >= 3 - ti) { rem -= 3 - ti; ++ti; }
  const int tj = ti + rem;
  const int i0 = ti * 256, j0 = tj * 256;
  const int tx = threadIdx.x & 31, ty = threadIdx.x >> 5;
  __shared__ float lds[32][33];
  const size_t cs = (size_t)NB * CH * CH;
  const _Float16* gp = GP + (size_t)b * CH * CH;
  _Float16* g = G + (size_t)b * CH * CH;

  for (int st = 0; st < 64; ++st) {
    const int sr = i0 + (st >> 3) * 32, sc = j0 + (st & 7) * 32;
    __syncthreads();
#pragma unroll
    for (int k = 0; k < 4; ++k) {
      const int r = ty + 8 * k;
      const size_t off = (size_t)(sr + r) * CH + sc + tx;
      float v = ((float)gp[off] + (float)gp[cs + off]) +
                ((float)gp[2 * cs + off] + (float)gp[3 * cs + off]);
      lds[r][tx] = v;
      g[off] = (_Float16)v;
    }
    if (ti != tj) {
      __syncthreads();
#pragma unroll
      for (int k = 0; k < 4; ++k) {
        const int r = ty + 8 * k;
        g[(size_t)(sc + r) * CH + sr + tx] = (_Float16)lds[tx][r];
      }
    }
  }
}

// ---------------------------------------------------------------------------
// Norms: INV[t*8+b][c] = 1/max(sqrt(sum_i Ut[t][b][c][i]*Wt[t*768+c][i]),eps)
// ---------------------------------------------------------------------------
__global__ void norm_kernel(const _Float16* __restrict__ Ut,
                            const _Float16* __restrict__ Wt,
                            float* __restrict__ INVv) {
  const int z = blockIdx.x;
  const int t = z >> 3;
  const int c = blockIdx.y * 128 + threadIdx.x;
  const _Float16* u = Ut + ((size_t)z * CH + c) * CH;
  const _Float16* wv = Wt + ((size_t)(t * CH + c)) * CH;
  float s = 0.f;
  for (int i = 0; i < CH; i += 8) {
    f16x8 uv = *(const f16x8*)(u + i);
    f16x8 wq = *(const f16x8*)(wv + i);
#pragma unroll
    for (int q = 0; q < 8; ++q) s += (float)uv[q] * (float)wq[q];
  }
  s = fmaxf(s, 0.f);
  INVv[(size_t)z * CH + c] = 1.0f / fmaxf(sqrtf(s), 1e-12f);
}

// ---------------------------------------------------------------------------
// Fused S = Wq-rows . Ut1-rows^T (96x96, K=768) via MFMA, scale, softmax
// over e, transposed fp16 ATt write. grid 64 (bh), 256 threads.
// ---------------------------------------------------------------------------
__global__ __launch_bounds__(256) void sattn_kernel(
    const _Float16* __restrict__ WT_, const _Float16* __restrict__ UT_,
    const float* __restrict__ INVv, const float* __restrict__ temp,
    _Float16* __restrict__ ATt) {
  const int bh = blockIdx.x;
  const int b = bh >> 3, h = bh & 7;
  __shared__ __align__(16) _Float16 lds[2][192 * 32];
  __shared__ float S[96][100];

  const int tid = threadIdx.x;
  const int l = tid & 63, w = tid >> 6;
  const int lo = l & 15, hi = l >> 4;
  const int wr = w >> 1, wc = w & 1;
  const int lr = l >> 2, lq = l & 3;

  const _Float16* Abase = WT_ + (size_t)(h * HD) * CH;
  const _Float16* Bbase = UT_ + ((size_t)(8 + b) * CH + h * HD) * CH;

  f32x4 acc[3][3];
#pragma unroll
  for (int i = 0; i < 3; ++i)
#pragma unroll
    for (int j = 0; j < 3; ++j)
      acc[i][j] = (f32x4){0.f, 0.f, 0.f, 0.f};

  auto STAGE = [&](int hb, int k0) {
#pragma unroll
    for (int c = 0; c < 3; ++c) {
      const int group = w * 3 + c;
      const int row = group * 16 + lr;
      const int ck = lq ^ ((row >> 1) & 3);
      const _Float16* src = (row < 96)
          ? Abase + (size_t)row * CH + k0 + 8 * ck
          : Bbase + (size_t)(row - 96) * CH + k0 + 8 * ck;
      gload16(src, &lds[hb][group * 512]);
    }
  };

  STAGE(0, 0);
  int cur = 0;
  for (int t = 0; t < 24; ++t) {
    if (t + 1 < 24) {
      STAGE(cur ^ 1, 32 * (t + 1));
      asm volatile("s_waitcnt vmcnt(3)" ::: "memory");
    } else {
      asm volatile("s_waitcnt vmcnt(0)" ::: "memory");
    }
    __builtin_amdgcn_s_barrier();

    f16x8 a[3], bb[3];
#pragma unroll
    for (int mi = 0; mi < 3; ++mi) {
      const int Ra = 48 * wr + 16 * mi + lo;
      a[mi] = *(const f16x8*)&lds[cur][Ra * 32 + (hi ^ ((Ra >> 1) & 3)) * 8];
    }
#pragma unroll
    for (int ni = 0; ni < 3; ++ni) {
      const int Rb = 96 + 48 * wc + 16 * ni + lo;
      bb[ni] = *(const f16x8*)&lds[cur][Rb * 32 + (hi ^ ((Rb >> 1) & 3)) * 8];
    }
#pragma unroll
    for (int mi = 0; mi < 3; ++mi)
#pragma unroll
      for (int ni = 0; ni < 3; ++ni)
        acc[mi][ni] = __builtin_amdgcn_mfma_f32_16x16x32_f16(
            a[mi], bb[ni], acc[mi][ni], 0, 0, 0);

    __builtin_amdgcn_s_barrier();
    cur ^= 1;
  }

  const float tv = temp[h];
  const float* iq = INVv + (size_t)b * CH + h * HD;
  const float* ik = INVv + (size_t)(8 + b) * CH + h * HD;
#pragma unroll
  for (int ni = 0; ni < 3; ++ni) {
    const int col = 48 * wc + 16 * ni + lo;
    const float ikv = ik[col];
#pragma unroll
    for (int mi = 0; mi < 3; ++mi) {
      const int rb = 48 * wr + 16 * mi + 4 * hi;
#pragma unroll
      for (int r = 0; r < 4; ++r)
        S[rb + r][col] = acc[mi][ni][r] * iq[rb + r] * ikv * tv;
    }
  }
  __syncthreads();

  const int g16 = tid >> 4, l16 = tid & 15;
  _Float16* ab = ATt + (size_t)bh * 9216;
#pragma unroll
  for (int it = 0; it < 6; ++it) {
    const int d = g16 + 16 * it;
    float v[6];
    float mx = -INFINITY;
#pragma unroll
    for (int j = 0; j < 6; ++j) { v[j] = S[d][l16 * 6 + j]; mx = fmaxf(mx, v[j]); }
#pragma unroll
    for (int m = 1; m < 16; m <<= 1) mx = fmaxf(mx, __shfl_xor(mx, m, 16));
    float sum = 0.f;
#pragma unroll
    for (int j = 0; j < 6; ++j) { v[j] = __expf(v[j] - mx); sum += v[j]; }
#pragma unroll
    for (int m = 1; m < 16; m <<= 1) sum += __shfl_xor(sum, m, 16);
    const float inv = 1.0f / sum;
#pragma unroll
    for (int j = 0; j < 6; ++j)
      ab[(size_t)(l16 * 6 + j) * 96 + d] = (_Float16)(v[j] * inv);
  }
}

// ---------------------------------------------------------------------------
// Mt[b][j][h*96+e] = sum_d Wpt[j][h96+d] * ATt[bh][e][d]
// ---------------------------------------------------------------------------
__global__ void mt_kernel(const _Float16* __restrict__ Wpt,
                          const _Float16* __restrict__ ATt,
                          _Float16* __restrict__ Mt) {
  const int j0 = blockIdx.x * 128;
  const int bh = blockIdx.y;
  const int b = bh >> 3, h = bh & 7;
  const int tx = threadIdx.x & 15, ty = threadIdx.x >> 4;
  __shared__ float Ws[16][128], Ats[16][96];
  float acc[8][6] = {};

  for (int d0 = 0; d0 < 96; d0 += 16) {
    {
      int jj = threadIdx.x >> 1, s8 = (threadIdx.x & 1) * 8;
      f16x8 v = *(const f16x8*)(Wpt + (size_t)(j0 + jj) * CH + h * HD + d0 + s8);
#pragma unroll
      for (int q = 0; q < 8; ++q) Ws[s8 + q][jj] = (float)v[q];
    }
    if (threadIdx.x < 192) {
      int e = threadIdx.x >> 1, s8 = (threadIdx.x & 1) * 8;
      f16x8 v = *(const f16x8*)(ATt + (size_t)bh * 9216 + (size_t)e * 96 + d0 + s8);
#pragma unroll
      for (int q = 0; q < 8; ++q) Ats[s8 + q][e] = (float)v[q];
    }
    __syncthreads();
#pragma unroll
    for (int kk = 0; kk < 16; ++kk) {
      float a[8], bb[6];
#pragma unroll
      for (int i = 0; i < 8; ++i) a[i] = Ws[kk][ty * 8 + i];
#pragma unroll
      for (int j = 0; j < 6; ++j) bb[j] = Ats[kk][tx * 6 + j];
#pragma unroll
      for (int i = 0; i < 8; ++i)
#pragma unroll
        for (int j = 0; j < 6; ++j)
          acc[i][j] += a[i] * bb[j];
    }
    __syncthreads();
  }

  _Float16* mb = Mt + (size_t)b * CH * CH;
#pragma unroll
  for (int i = 0; i < 8; ++i)
#pragma unroll
    for (int j = 0; j < 6; ++j)
      mb[(size_t)(j0 + ty * 8 + i) * CH + h * HD + tx * 6 + j] = (_Float16)acc[i][j];
}

// ---------------------------------------------------------------------------
extern "C" void kernel_launch(void* const* d_in, const int* in_sizes, int n_in,
                              void* d_out, int out_size, void* d_ws, size_t ws_size,
                              hipStream_t stream) {
  const float* x      = (const float*)d_in[0];
  const float* W_qkv  = (const float*)d_in[1];
  const float* W_proj = (const float*)d_in[2];
  const float* b_proj = (const float*)d_in[3];
  const float* temp   = (const float*)d_in[4];
  float* out = (float*)d_out;
  char* ws = (char*)d_ws;

  _Float16* XT  = (_Float16*)(ws + XT_B);
  _Float16* UT  = (_Float16*)(ws + UT_B);
  _Float16* ATT = (_Float16*)(ws + ATT_B);
  _Float16* MT  = (_Float16*)(ws + MT_B);
  _Float16* PT  = (_Float16*)(ws + PT_B);
  _Float16* GP  = (_Float16*)(ws + GP_B);
  _Float16* XH  = (_Float16*)(ws + XH_B);
  _Float16* WH  = (_Float16*)(ws + WH_B);
  _Float16* WT  = (_Float16*)(ws + WT_B);
  _Float16* WPT = (_Float16*)(ws + WPT_B);
  _Float16* G   = (_Float16*)(ws + G_B);
  float*    INV = (float*)   (ws + INV_B);

  const bool fast = ws_size >= XH2_B + XH_BYTES;   // 168.7 MB
  _Float16* XHU = fast ? (_Float16*)(ws + XH2_B) : XH;

  const long CC = (long)CH * CH;           // 589824
  const long SC = (long)SEQ * CH;          // 3145728

  // --- weight converts / transposes; x -> XT (+XH if fast) ---
  cvt_f16_kernel<<<(CH * NC3 / 4 + 255) / 256, 256, 0, stream>>>(
      W_qkv, WH, CH * NC3 / 4);
  transpose_cvt_kernel<<<dim3(CH / 32, SEQ / 32, NB), 256, 0, stream>>>(
      x, XT, fast ? XHU : nullptr, SEQ, CH, SC, SC);
  transpose_cvt_kernel<<<dim3(NC3 / 32, CH / 32, 1), 256, 0, stream>>>(
      W_qkv, WT, nullptr, CH, NC3, 0, 0);
  transpose_cvt_kernel<<<dim3(CH / 32, CH / 32, 1), 256, 0, stream>>>(
      W_proj, WPT, nullptr, CH, CH, 0, 0);

  // --- G upper-tri partials: 6 tiles x (8 b x 4 K-chunks) = 192 blocks ---
  gemm_bt_256<true, false, true><<<192, 512, 0, stream>>>(
      XT, XT, nullptr, GP, 1024, SEQ, SEQ, CH,
      (long)CH * SEQ, (long)CH * SEQ, CC, NB, 1024, 1024, (long)NB * CC,
      3, 1);

  // --- reduce chunks + mirror to full symmetric G ---
  reduce_mirror_kernel<<<dim3(6, NB), 256, 0, stream>>>(GP, G);

  // --- U fused over t: UT[t][b] = Wt_t . G_b^T  (z = t*8+b), 128-tile,
  //     576 blocks (proven round-6 config: full machine, 5 blocks/CU) ---
  gemm_bt_128<true, false><<<576, 256, 0, stream>>>(
      WT, G, nullptr, UT, CH, CH, CH, CH,
      0, CC, CC, NB, CC, 0, (long)NB * CC, 6, 6);

  // --- norms ---
  norm_kernel<<<dim3(16, 6), 128, 0, stream>>>(UT, WT, INV);

  // --- fused S + scale + softmax -> ATt ---
  sattn_kernel<<<64, 256, 0, stream>>>(WT, UT, INV, temp, ATT);

  // --- Mt ---
  mt_kernel<<<dim3(6, 64), 256, 0, stream>>>(WPT, ATT, MT);

  // --- Pt_b = Mt_b . Wv^T (128-tile kernel, 288 blocks) ---
  gemm_bt_128<true, false><<<288, 256, 0, stream>>>(
      MT, WH + 2 * CH, nullptr, PT, CH, CH, NC3, CH,
      CC, 0, CC, NB, 0, 0, 0, 6, 6);

  // --- fallback: x -> XH (GP dead after reduce_mirror) ---
  if (!fast)
    cvt_f16_kernel<<<(int)(NB * SC / 4 / 256), 256, 0, stream>>>(
        x, XH, (int)(NB * SC / 4));

  // --- out_b = XH_b . Pt_b^T + bias  (M=4096, N=768, K=768), 384 blocks ---
  gemm_bt_256<false, true, false><<<384, 512, 0, stream>>>(
      XHU, PT, b_proj, out, CH, CH, CH, CH,
      SC, CC, SC, NB, 0, 0, 0, 3, 16);
}

// Round 9
// 274.749 us; speedup vs baseline: 1.1363x; 1.1363x over previous
//
#include <hip/hip_runtime.h>
#include <math.h>

// Problem constants (b=8, n=4096, c=768, h=8, d=96)
#define NB  8
#define SEQ 4096
#define CH  768
#define NH  8
#define HD  96
#define NC3 2304   // 3*CH

typedef _Float16 f16x8 __attribute__((ext_vector_type(8)));
typedef float    f32x4 __attribute__((ext_vector_type(4)));

// ---------------------------------------------------------------------------
// Workspace layout (BYTE offsets). Base = 118,407,168 B (proven). Optional
// XH2 (fp16 x row-major) appended if ws_size >= 168,738,816.
// ---------------------------------------------------------------------------
static const size_t XT_B   = 0;           // fp16 x^T [b][c][n]; dies after G
static const size_t UT_B   = 0;           // overlays XT
static const size_t ATT_B  = 28311552;
static const size_t MT_B   = 29491200;
static const size_t PT_B   = 38928384;
static const size_t GP_B   = 50331648;    // G partials; dies after reduce
static const size_t XH_B   = 50331648;    // fallback XH (fills after reduce)
static const size_t WH_B   = 100663296;
static const size_t WT_B   = 104202240;
static const size_t WPT_B  = 107741184;
static const size_t G_B    = 108920832;
static const size_t INV_B  = 118358016;
static const size_t XH2_B  = 118407168;   // fast-path XH (needs big ws)
static const size_t XH_BYTES = (size_t)NB * SEQ * CH * 2;   // 50,331,648

// ---------------------------------------------------------------------------
// async global->LDS, 16 B per lane (wave-uniform LDS base + lane*16)
// ---------------------------------------------------------------------------
__device__ __forceinline__ void gload16(const void* g, void* l) {
  __builtin_amdgcn_global_load_lds(
      (const __attribute__((address_space(1))) void*)g,
      (__attribute__((address_space(3))) void*)l, 16, 0, 0);
}

// ---------------------------------------------------------------------------
// Elementwise fp32 -> fp16 convert
// ---------------------------------------------------------------------------
__global__ void cvt_f16_kernel(const float* __restrict__ in,
                               _Float16* __restrict__ out, int n4) {
  int i = blockIdx.x * blockDim.x + threadIdx.x;
  if (i < n4) {
    float4 v = *(const float4*)(in + (size_t)i * 4);
    _Float16* o = out + (size_t)i * 4;
    o[0] = (_Float16)v.x; o[1] = (_Float16)v.y;
    o[2] = (_Float16)v.z; o[3] = (_Float16)v.w;
  }
}

// ---------------------------------------------------------------------------
// Tiled transpose+convert: fp32 [R][C] -> fp16 [C][R]; optional fp16 [R][C].
// ---------------------------------------------------------------------------
__global__ void transpose_cvt_kernel(const float* __restrict__ in,
                                     _Float16* __restrict__ outT,
                                     _Float16* __restrict__ outH,
                                     int R, int C, long sIn, long sOut) {
  __shared__ float t[32][33];
  const int b = blockIdx.z;
  const int c0 = blockIdx.x * 32, r0 = blockIdx.y * 32;
  const int tx = threadIdx.x & 31, ty = threadIdx.x >> 5;
  const float* ib = in + (size_t)b * sIn;
  _Float16* ob = outT + (size_t)b * sOut;
#pragma unroll
  for (int k = 0; k < 4; ++k) {
    float v = ib[(size_t)(r0 + ty + 8 * k) * C + c0 + tx];
    t[ty + 8 * k][tx] = v;
    if (outH)
      outH[(size_t)b * sOut + (size_t)(r0 + ty + 8 * k) * C + c0 + tx] = (_Float16)v;
  }
  __syncthreads();
#pragma unroll
  for (int k = 0; k < 4; ++k)
    ob[(size_t)(c0 + ty + 8 * k) * R + r0 + tx] = (_Float16)t[tx][ty + 8 * k];
}

// ---------------------------------------------------------------------------
// 128x128 4-wave 2-phase GEMM (proven, round-6 config) — G / Pt.
// TRI: upper-tri gx*gx 128-tiling for symmetric output.
// ---------------------------------------------------------------------------
template<bool FP16OUT, bool BIAS, bool TRI>
__global__ __launch_bounds__(256) void gemm_bt_mfma(
    const _Float16* __restrict__ Ap, const _Float16* __restrict__ Bp,
    const float* __restrict__ bias, void* __restrict__ Cp,
    int K, int lda, int ldb, int ldc,
    long sA, long sB, long sC, int zdiv, long aCS, long bCS, long cCS,
    int gx, int gy) {
  __shared__ __align__(16) _Float16 ldsA[2][128 * 32];
  __shared__ __align__(16) _Float16 ldsB[2][128 * 32];

  const int nwg = gridDim.x;
  const int lid = blockIdx.x;
  const int wg = (lid & 7) * (nwg >> 3) + (lid >> 3);
  int bx, by, z;
  if constexpr (TRI) {
    int tt = wg % 21; z = wg / 21;
    int ti = 0, rem = tt;
    while (rem >= 6 - ti) { rem -= 6 - ti; ++ti; }
    by = ti; bx = ti + rem;
  } else {
    bx = wg % gx; int r2 = wg / gx; by = r2 % gy; z = r2 / gy;
  }
  const int bat = z % zdiv, chk = z / zdiv;
  const _Float16* A = Ap + (size_t)bat * sA + (size_t)chk * aCS;
  const _Float16* B = Bp + (size_t)bat * sB + (size_t)chk * bCS;
  const size_t cOff = (size_t)bat * sC + (size_t)chk * cCS;

  const int row0 = by * 128, col0 = bx * 128;
  const int tid = threadIdx.x;
  const int l = tid & 63, w = tid >> 6;
  const int lo = l & 15, hi = l >> 4;
  const int wr = w >> 1, wc = w & 1;
  const int rw = 32 * w;
  const int lr = l >> 2;
  const int ls = l & 3;

  f32x4 acc[4][4];
#pragma unroll
  for (int i = 0; i < 4; ++i)
#pragma unroll
    for (int j = 0; j < 4; ++j)
      acc[i][j] = (f32x4){0.f, 0.f, 0.f, 0.f};

  auto STAGE = [&](int hb, int k0) {
#pragma unroll
    for (int q = 0; q < 2; ++q) {
      const int r = rw + 16 * q + lr;
      const int ck = ls ^ ((r >> 1) & 3);
      gload16(A + (size_t)(row0 + r) * lda + k0 + 8 * ck,
              &ldsA[hb][(rw + 16 * q) * 32]);
      gload16(B + (size_t)(col0 + r) * ldb + k0 + 8 * ck,
              &ldsB[hb][(rw + 16 * q) * 32]);
    }
  };

  STAGE(0, 0);
  const int nt = K / 32;
  int cur = 0;
  for (int t = 0; t < nt; ++t) {
    if (t + 1 < nt) {
      STAGE(cur ^ 1, 32 * (t + 1));
      asm volatile("s_waitcnt vmcnt(4)" ::: "memory");
    } else {
      asm volatile("s_waitcnt vmcnt(0)" ::: "memory");
    }
    __builtin_amdgcn_s_barrier();

    f16x8 a[4], b[4];
#pragma unroll
    for (int mi = 0; mi < 4; ++mi) {
      int Ra = 64 * wr + 16 * mi + lo;
      a[mi] = *(const f16x8*)&ldsA[cur][Ra * 32 + (hi ^ ((Ra >> 1) & 3)) * 8];
    }
#pragma unroll
    for (int ni = 0; ni < 4; ++ni) {
      int Rb = 64 * wc + 16 * ni + lo;
      b[ni] = *(const f16x8*)&ldsB[cur][Rb * 32 + (hi ^ ((Rb >> 1) & 3)) * 8];
    }
#pragma unroll
    for (int mi = 0; mi < 4; ++mi)
#pragma unroll
      for (int ni = 0; ni < 4; ++ni)
        acc[mi][ni] = __builtin_amdgcn_mfma_f32_16x16x32_f16(
            a[mi], b[ni], acc[mi][ni], 0, 0, 0);

    __builtin_amdgcn_s_barrier();
    cur ^= 1;
  }

#pragma unroll
  for (int ni = 0; ni < 4; ++ni) {
    const int col = col0 + 64 * wc + 16 * ni + lo;
    float bv = 0.f;
    if constexpr (BIAS) bv = bias[col];
#pragma unroll
    for (int mi = 0; mi < 4; ++mi) {
      const int rowb = row0 + 64 * wr + 16 * mi + 4 * hi;
#pragma unroll
      for (int r = 0; r < 4; ++r) {
        float v = acc[mi][ni][r] + bv;
        if constexpr (FP16OUT)
          ((_Float16*)Cp)[cOff + (size_t)(rowb + r) * ldc + col] = (_Float16)v;
        else
          ((float*)Cp)[cOff + (size_t)(rowb + r) * ldc + col] = v;
      }
    }
  }
}

// ---------------------------------------------------------------------------
// 256x128-tile 8-wave 2-phase GEMM — higher arithmetic intensity (85 FLOP/B
// vs 64) to clear the per-CU L2 staging-BW limit. Per-wave structure is
// IDENTICAL to the proven 128x128 kernel (64x64 out, 4x4 frags, 8 ds_read,
// 16 MFMA per K-step); only the staging footprint differs (256 A-rows by all
// 8 waves; 128 B-rows by waves 0-3). LDS 48 KB -> 3 blocks/CU.
// Requires M%256==0, N%128==0, K%32==0. nwg%8==0 for XCD swizzle.
// ---------------------------------------------------------------------------
template<bool FP16OUT, bool BIAS>
__global__ __launch_bounds__(512) void gemm_bt_wide(
    const _Float16* __restrict__ Ap, const _Float16* __restrict__ Bp,
    const float* __restrict__ bias, void* __restrict__ Cp,
    int K, int lda, int ldb, int ldc,
    long sA, long sB, long sC, int zdiv, long aCS, long bCS, long cCS,
    int gx, int gy) {
  __shared__ __align__(16) _Float16 ldsA[2][256 * 32];   // 32 KB
  __shared__ __align__(16) _Float16 ldsB[2][128 * 32];   // 16 KB

  const int nwg = gridDim.x;
  const int lid = blockIdx.x;
  const int wg = (lid & 7) * (nwg >> 3) + (lid >> 3);
  int bx = wg % gx; int r2 = wg / gx; int by = r2 % gy; int z = r2 / gy;
  const int bat = z % zdiv, chk = z / zdiv;
  const _Float16* A = Ap + (size_t)bat * sA + (size_t)chk * aCS;
  const _Float16* B = Bp + (size_t)bat * sB + (size_t)chk * bCS;
  const size_t cOff = (size_t)bat * sC + (size_t)chk * cCS;

  const int row0 = by * 256, col0 = bx * 128;
  const int tid = threadIdx.x;
  const int l = tid & 63, w = tid >> 6;     // 8 waves
  const int lo = l & 15, hi = l >> 4;
  const int wr = w >> 1, wc = w & 1;        // 4M x 2N wave grid, 64x64 each
  const int rw = 32 * w;                    // A staging rows 32w..32w+31
  const int lr = l >> 2;
  const int ls = l & 3;

  f32x4 acc[4][4];
#pragma unroll
  for (int i = 0; i < 4; ++i)
#pragma unroll
    for (int j = 0; j < 4; ++j)
      acc[i][j] = (f32x4){0.f, 0.f, 0.f, 0.f};

  // A: 8 waves x 2 calls x 16 rows = 256 rows. B: waves 0-3 only, 128 rows.
  auto STAGE = [&](int hb, int k0) {
#pragma unroll
    for (int q = 0; q < 2; ++q) {
      const int r = rw + 16 * q + lr;
      const int ck = ls ^ ((r >> 1) & 3);
      gload16(A + (size_t)(row0 + r) * lda + k0 + 8 * ck,
              &ldsA[hb][(rw + 16 * q) * 32]);
      if (w < 4)
        gload16(B + (size_t)(col0 + r) * ldb + k0 + 8 * ck,
                &ldsB[hb][(rw + 16 * q) * 32]);
    }
  };

  STAGE(0, 0);
  const int nt = K / 32;
  int cur = 0;
  for (int t = 0; t < nt; ++t) {
    if (t + 1 < nt) {
      STAGE(cur ^ 1, 32 * (t + 1));
      if (w < 4)   // wave-uniform branch; these waves have 4 loads/iter
        asm volatile("s_waitcnt vmcnt(4)" ::: "memory");
      else         // A-only waves: 2 loads/iter
        asm volatile("s_waitcnt vmcnt(2)" ::: "memory");
    } else {
      asm volatile("s_waitcnt vmcnt(0)" ::: "memory");
    }
    __builtin_amdgcn_s_barrier();

    f16x8 a[4], b[4];
#pragma unroll
    for (int mi = 0; mi < 4; ++mi) {
      int Ra = 64 * wr + 16 * mi + lo;        // 0..255
      a[mi] = *(const f16x8*)&ldsA[cur][Ra * 32 + (hi ^ ((Ra >> 1) & 3)) * 8];
    }
#pragma unroll
    for (int ni = 0; ni < 4; ++ni) {
      int Rb = 64 * wc + 16 * ni + lo;        // 0..127
      b[ni] = *(const f16x8*)&ldsB[cur][Rb * 32 + (hi ^ ((Rb >> 1) & 3)) * 8];
    }
#pragma unroll
    for (int mi = 0; mi < 4; ++mi)
#pragma unroll
      for (int ni = 0; ni < 4; ++ni)
        acc[mi][ni] = __builtin_amdgcn_mfma_f32_16x16x32_f16(
            a[mi], b[ni], acc[mi][ni], 0, 0, 0);

    __builtin_amdgcn_s_barrier();
    cur ^= 1;
  }

#pragma unroll
  for (int ni = 0; ni < 4; ++ni) {
    const int col = col0 + 64 * wc + 16 * ni + lo;
    float bv = 0.f;
    if constexpr (BIAS) bv = bias[col];
#pragma unroll
    for (int mi = 0; mi < 4; ++mi) {
      const int rowb = row0 + 64 * wr + 16 * mi + 4 * hi;
#pragma unroll
      for (int r = 0; r < 4; ++r) {
        float v = acc[mi][ni][r] + bv;
        if constexpr (FP16OUT)
          ((_Float16*)Cp)[cOff + (size_t)(rowb + r) * ldc + col] = (_Float16)v;
        else
          ((float*)Cp)[cOff + (size_t)(rowb + r) * ldc + col] = v;
      }
    }
  }
}

// ---------------------------------------------------------------------------
// Reduce 4 split-K chunks of the 21 upper-tri 128-tiles and mirror to full G.
// grid (21, 8), block 256.
// ---------------------------------------------------------------------------
__global__ void reduce_mirror_kernel(const _Float16* __restrict__ GP,
                                     _Float16* __restrict__ G) {
  const int t = blockIdx.x, b = blockIdx.y;
  int ti = 0, rem = t;
  while (rem >= 6 - ti) { rem -= 6 - ti; ++ti; }
  const int tj = ti + rem;
  const int i0 = ti * 128, j0 = tj * 128;
  const int tx = threadIdx.x & 31, ty = threadIdx.x >> 5;
  __shared__ float lds[32][33];
  const size_t cs = (size_t)NB * CH * CH;
  const _Float16* gp = GP + (size_t)b * CH * CH;
  _Float16* g = G + (size_t)b * CH * CH;

  for (int st = 0; st < 16; ++st) {
    const int sr = i0 + (st >> 2) * 32, sc = j0 + (st & 3) * 32;
    __syncthreads();
#pragma unroll
    for (int k = 0; k < 4; ++k) {
      const int r = ty + 8 * k;
      const size_t off = (size_t)(sr + r) * CH + sc + tx;
      float v = ((float)gp[off] + (float)gp[cs + off]) +
                ((float)gp[2 * cs + off] + (float)gp[3 * cs + off]);
      lds[r][tx] = v;
      g[off] = (_Float16)v;
    }
    if (ti != tj) {
      __syncthreads();
#pragma unroll
      for (int k = 0; k < 4; ++k) {
        const int r = ty + 8 * k;
        g[(size_t)(sc + r) * CH + sr + tx] = (_Float16)lds[tx][r];
      }
    }
  }
}

// ---------------------------------------------------------------------------
// Norms: INV[t*8+b][c] = 1/max(sqrt(sum_i Ut[t][b][c][i]*Wt[t*768+c][i]),eps)
// ---------------------------------------------------------------------------
__global__ void norm_kernel(const _Float16* __restrict__ Ut,
                            const _Float16* __restrict__ Wt,
                            float* __restrict__ INVv) {
  const int z = blockIdx.x;
  const int t = z >> 3;
  const int c = blockIdx.y * 128 + threadIdx.x;
  const _Float16* u = Ut + ((size_t)z * CH + c) * CH;
  const _Float16* wv = Wt + ((size_t)(t * CH + c)) * CH;
  float s = 0.f;
  for (int i = 0; i < CH; i += 8) {
    f16x8 uv = *(const f16x8*)(u + i);
    f16x8 wq = *(const f16x8*)(wv + i);
#pragma unroll
    for (int q = 0; q < 8; ++q) s += (float)uv[q] * (float)wq[q];
  }
  s = fmaxf(s, 0.f);
  INVv[(size_t)z * CH + c] = 1.0f / fmaxf(sqrtf(s), 1e-12f);
}

// ---------------------------------------------------------------------------
// Fused S = Wq-rows . Ut1-rows^T (96x96, K=768) via MFMA, scale, softmax
// over e, transposed fp16 ATt write. grid 64 (bh), 256 threads.
// ---------------------------------------------------------------------------
__global__ __launch_bounds__(256) void sattn_kernel(
    const _Float16* __restrict__ WT_, const _Float16* __restrict__ UT_,
    const float* __restrict__ INVv, const float* __restrict__ temp,
    _Float16* __restrict__ ATt) {
  const int bh = blockIdx.x;
  const int b = bh >> 3, h = bh & 7;
  __shared__ __align__(16) _Float16 lds[2][192 * 32];
  __shared__ float S[96][100];

  const int tid = threadIdx.x;
  const int l = tid & 63, w = tid >> 6;
  const int lo = l & 15, hi = l >> 4;
  const int wr = w >> 1, wc = w & 1;
  const int lr = l >> 2, lq = l & 3;

  const _Float16* Abase = WT_ + (size_t)(h * HD) * CH;
  const _Float16* Bbase = UT_ + ((size_t)(8 + b) * CH + h * HD) * CH;

  f32x4 acc[3][3];
#pragma unroll
  for (int i = 0; i < 3; ++i)
#pragma unroll
    for (int j = 0; j < 3; ++j)
      acc[i][j] = (f32x4){0.f, 0.f, 0.f, 0.f};

  auto STAGE = [&](int hb, int k0) {
#pragma unroll
    for (int c = 0; c < 3; ++c) {
      const int group = w * 3 + c;
      const int row = group * 16 + lr;
      const int ck = lq ^ ((row >> 1) & 3);
      const _Float16* src = (row < 96)
          ? Abase + (size_t)row * CH + k0 + 8 * ck
          : Bbase + (size_t)(row - 96) * CH + k0 + 8 * ck;
      gload16(src, &lds[hb][group * 512]);
    }
  };

  STAGE(0, 0);
  int cur = 0;
  for (int t = 0; t < 24; ++t) {
    if (t + 1 < 24) {
      STAGE(cur ^ 1, 32 * (t + 1));
      asm volatile("s_waitcnt vmcnt(3)" ::: "memory");
    } else {
      asm volatile("s_waitcnt vmcnt(0)" ::: "memory");
    }
    __builtin_amdgcn_s_barrier();

    f16x8 a[3], bb[3];
#pragma unroll
    for (int mi = 0; mi < 3; ++mi) {
      const int Ra = 48 * wr + 16 * mi + lo;
      a[mi] = *(const f16x8*)&lds[cur][Ra * 32 + (hi ^ ((Ra >> 1) & 3)) * 8];
    }
#pragma unroll
    for (int ni = 0; ni < 3; ++ni) {
      const int Rb = 96 + 48 * wc + 16 * ni + lo;
      bb[ni] = *(const f16x8*)&lds[cur][Rb * 32 + (hi ^ ((Rb >> 1) & 3)) * 8];
    }
#pragma unroll
    for (int mi = 0; mi < 3; ++mi)
#pragma unroll
      for (int ni = 0; ni < 3; ++ni)
        acc[mi][ni] = __builtin_amdgcn_mfma_f32_16x16x32_f16(
            a[mi], bb[ni], acc[mi][ni], 0, 0, 0);

    __builtin_amdgcn_s_barrier();
    cur ^= 1;
  }

  const float tv = temp[h];
  const float* iq = INVv + (size_t)b * CH + h * HD;
  const float* ik = INVv + (size_t)(8 + b) * CH + h * HD;
#pragma unroll
  for (int ni = 0; ni < 3; ++ni) {
    const int col = 48 * wc + 16 * ni + lo;
    const float ikv = ik[col];
#pragma unroll
    for (int mi = 0; mi < 3; ++mi) {
      const int rb = 48 * wr + 16 * mi + 4 * hi;
#pragma unroll
      for (int r = 0; r < 4; ++r)
        S[rb + r][col] = acc[mi][ni][r] * iq[rb + r] * ikv * tv;
    }
  }
  __syncthreads();

  const int g16 = tid >> 4, l16 = tid & 15;
  _Float16* ab = ATt + (size_t)bh * 9216;
#pragma unroll
  for (int it = 0; it < 6; ++it) {
    const int d = g16 + 16 * it;
    float v[6];
    float mx = -INFINITY;
#pragma unroll
    for (int j = 0; j < 6; ++j) { v[j] = S[d][l16 * 6 + j]; mx = fmaxf(mx, v[j]); }
#pragma unroll
    for (int m = 1; m < 16; m <<= 1) mx = fmaxf(mx, __shfl_xor(mx, m, 16));
    float sum = 0.f;
#pragma unroll
    for (int j = 0; j < 6; ++j) { v[j] = __expf(v[j] - mx); sum += v[j]; }
#pragma unroll
    for (int m = 1; m < 16; m <<= 1) sum += __shfl_xor(sum, m, 16);
    const float inv = 1.0f / sum;
#pragma unroll
    for (int j = 0; j < 6; ++j)
      ab[(size_t)(l16 * 6 + j) * 96 + d] = (_Float16)(v[j] * inv);
  }
}

// ---------------------------------------------------------------------------
// Mt[b][j][h*96+e] = sum_d Wpt[j][h96+d] * ATt[bh][e][d]
// ---------------------------------------------------------------------------
__global__ void mt_kernel(const _Float16* __restrict__ Wpt,
                          const _Float16* __restrict__ ATt,
                          _Float16* __restrict__ Mt) {
  const int j0 = blockIdx.x * 128;
  const int bh = blockIdx.y;
  const int b = bh >> 3, h = bh & 7;
  const int tx = threadIdx.x & 15, ty = threadIdx.x >> 4;
  __shared__ float Ws[16][128], Ats[16][96];
  float acc[8][6] = {};

  for (int d0 = 0; d0 < 96; d0 += 16) {
    {
      int jj = threadIdx.x >> 1, s8 = (threadIdx.x & 1) * 8;
      f16x8 v = *(const f16x8*)(Wpt + (size_t)(j0 + jj) * CH + h * HD + d0 + s8);
#pragma unroll
      for (int q = 0; q < 8; ++q) Ws[s8 + q][jj] = (float)v[q];
    }
    if (threadIdx.x < 192) {
      int e = threadIdx.x >> 1, s8 = (threadIdx.x & 1) * 8;
      f16x8 v = *(const f16x8*)(ATt + (size_t)bh * 9216 + (size_t)e * 96 + d0 + s8);
#pragma unroll
      for (int q = 0; q < 8; ++q) Ats[s8 + q][e] = (float)v[q];
    }
    __syncthreads();
#pragma unroll
    for (int kk = 0; kk < 16; ++kk) {
      float a[8], bb[6];
#pragma unroll
      for (int i = 0; i < 8; ++i) a[i] = Ws[kk][ty * 8 + i];
#pragma unroll
      for (int j = 0; j < 6; ++j) bb[j] = Ats[kk][tx * 6 + j];
#pragma unroll
      for (int i = 0; i < 8; ++i)
#pragma unroll
        for (int j = 0; j < 6; ++j)
          acc[i][j] += a[i] * bb[j];
    }
    __syncthreads();
  }

  _Float16* mb = Mt + (size_t)b * CH * CH;
#pragma unroll
  for (int i = 0; i < 8; ++i)
#pragma unroll
    for (int j = 0; j < 6; ++j)
      mb[(size_t)(j0 + ty * 8 + i) * CH + h * HD + tx * 6 + j] = (_Float16)acc[i][j];
}

// ---------------------------------------------------------------------------
extern "C" void kernel_launch(void* const* d_in, const int* in_sizes, int n_in,
                              void* d_out, int out_size, void* d_ws, size_t ws_size,
                              hipStream_t stream) {
  const float* x      = (const float*)d_in[0];
  const float* W_qkv  = (const float*)d_in[1];
  const float* W_proj = (const float*)d_in[2];
  const float* b_proj = (const float*)d_in[3];
  const float* temp   = (const float*)d_in[4];
  float* out = (float*)d_out;
  char* ws = (char*)d_ws;

  _Float16* XT  = (_Float16*)(ws + XT_B);
  _Float16* UT  = (_Float16*)(ws + UT_B);
  _Float16* ATT = (_Float16*)(ws + ATT_B);
  _Float16* MT  = (_Float16*)(ws + MT_B);
  _Float16* PT  = (_Float16*)(ws + PT_B);
  _Float16* GP  = (_Float16*)(ws + GP_B);
  _Float16* XH  = (_Float16*)(ws + XH_B);
  _Float16* WH  = (_Float16*)(ws + WH_B);
  _Float16* WT  = (_Float16*)(ws + WT_B);
  _Float16* WPT = (_Float16*)(ws + WPT_B);
  _Float16* G   = (_Float16*)(ws + G_B);
  float*    INV = (float*)   (ws + INV_B);

  const bool fast = ws_size >= XH2_B + XH_BYTES;   // 168.7 MB
  _Float16* XHU = fast ? (_Float16*)(ws + XH2_B) : XH;

  const long CC = (long)CH * CH;           // 589824
  const long SC = (long)SEQ * CH;          // 3145728

  // --- weight converts / transposes; x -> XT (+XH if fast) ---
  cvt_f16_kernel<<<(CH * NC3 / 4 + 255) / 256, 256, 0, stream>>>(
      W_qkv, WH, CH * NC3 / 4);
  transpose_cvt_kernel<<<dim3(CH / 32, SEQ / 32, NB), 256, 0, stream>>>(
      x, XT, fast ? XHU : nullptr, SEQ, CH, SC, SC);
  transpose_cvt_kernel<<<dim3(NC3 / 32, CH / 32, 1), 256, 0, stream>>>(
      W_qkv, WT, nullptr, CH, NC3, 0, 0);
  transpose_cvt_kernel<<<dim3(CH / 32, CH / 32, 1), 256, 0, stream>>>(
      W_proj, WPT, nullptr, CH, CH, 0, 0);

  // --- G upper-tri partials: 21 tiles x (8 b x 4 K-chunks) = 672 blocks ---
  gemm_bt_mfma<true, false, true><<<672, 256, 0, stream>>>(
      XT, XT, nullptr, GP, 1024, SEQ, SEQ, CH,
      (long)CH * SEQ, (long)CH * SEQ, CC, NB, 1024, 1024, (long)NB * CC,
      21, 1);

  // --- reduce chunks + mirror to full symmetric G ---
  reduce_mirror_kernel<<<dim3(21, NB), 256, 0, stream>>>(GP, G);

  // --- U fused over t: UT[t][b] = Wt_t . G_b^T  (z = t*8+b),
  //     256x128 tiles: 3 M x 6 N x 16 z = 288 blocks, all co-resident ---
  gemm_bt_wide<true, false><<<288, 512, 0, stream>>>(
      WT, G, nullptr, UT, CH, CH, CH, CH,
      0, CC, CC, NB, CC, 0, (long)NB * CC, 6, 3);

  // --- norms ---
  norm_kernel<<<dim3(16, 6), 128, 0, stream>>>(UT, WT, INV);

  // --- fused S + scale + softmax -> ATt ---
  sattn_kernel<<<64, 256, 0, stream>>>(WT, UT, INV, temp, ATT);

  // --- Mt ---
  mt_kernel<<<dim3(6, 64), 256, 0, stream>>>(WPT, ATT, MT);

  // --- Pt_b = Mt_b . Wv^T (128-tile kernel, 288 blocks) ---
  gemm_bt_mfma<true, false, false><<<288, 256, 0, stream>>>(
      MT, WH + 2 * CH, nullptr, PT, CH, CH, NC3, CH,
      CC, 0, CC, NB, 0, 0, 0, 6, 6);

  // --- fallback: x -> XH (GP dead after reduce_mirror) ---
  if (!fast)
    cvt_f16_kernel<<<(int)(NB * SC / 4 / 256), 256, 0, stream>>>(
        x, XH, (int)(NB * SC / 4));

  // --- out_b = XH_b . Pt_b^T + bias:
  //     256x128 tiles: 16 M x 6 N x 8 b = 768 blocks = 3 exact rounds ---
  gemm_bt_wide<false, true><<<768, 512, 0, stream>>>(
      XHU, PT, b_proj, out, CH, CH, CH, CH,
      SC, CC, SC, NB, 0, 0, 0, 6, 16);
}

// Round 10
// 266.941 us; speedup vs baseline: 1.1696x; 1.0292x over previous
//
#include <hip/hip_runtime.h>
#include <math.h>

// Problem constants (b=8, n=4096, c=768, h=8, d=96)
#define NB  8
#define SEQ 4096
#define CH  768
#define NH  8
#define HD  96
#define NC3 2304   // 3*CH

typedef _Float16 f16x8 __attribute__((ext_vector_type(8)));
typedef float    f32x4 __attribute__((ext_vector_type(4)));

// ---------------------------------------------------------------------------
// Workspace layout (BYTE offsets). Base = 118,407,168 B (proven). Optional
// XH2 (fp16 x row-major) appended if ws_size >= 168,738,816.
// ---------------------------------------------------------------------------
static const size_t XT_B   = 0;           // fp16 x^T [b][c][n]; dies after G
static const size_t UT_B   = 0;           // overlays XT
static const size_t ATT_B  = 28311552;
static const size_t MT_B   = 29491200;
static const size_t PT_B   = 38928384;
static const size_t GP_B   = 50331648;    // G partials; dies after reduce
static const size_t XH_B   = 50331648;    // fallback XH (fills after reduce)
static const size_t WH_B   = 100663296;
static const size_t WT_B   = 104202240;
static const size_t WPT_B  = 107741184;
static const size_t G_B    = 108920832;
static const size_t INV_B  = 118358016;
static const size_t XH2_B  = 118407168;   // fast-path XH (needs big ws)
static const size_t XH_BYTES = (size_t)NB * SEQ * CH * 2;   // 50,331,648

// ---------------------------------------------------------------------------
// async global->LDS, 16 B per lane (wave-uniform LDS base + lane*16)
// ---------------------------------------------------------------------------
__device__ __forceinline__ void gload16(const void* g, void* l) {
  __builtin_amdgcn_global_load_lds(
      (const __attribute__((address_space(1))) void*)g,
      (__attribute__((address_space(3))) void*)l, 16, 0, 0);
}

// ---------------------------------------------------------------------------
// Elementwise fp32 -> fp16 convert
// ---------------------------------------------------------------------------
__global__ void cvt_f16_kernel(const float* __restrict__ in,
                               _Float16* __restrict__ out, int n4) {
  int i = blockIdx.x * blockDim.x + threadIdx.x;
  if (i < n4) {
    float4 v = *(const float4*)(in + (size_t)i * 4);
    _Float16* o = out + (size_t)i * 4;
    o[0] = (_Float16)v.x; o[1] = (_Float16)v.y;
    o[2] = (_Float16)v.z; o[3] = (_Float16)v.w;
  }
}

// ---------------------------------------------------------------------------
// Tiled transpose+convert: fp32 [R][C] -> fp16 [C][R]; optional fp16 [R][C].
// ---------------------------------------------------------------------------
__global__ void transpose_cvt_kernel(const float* __restrict__ in,
                                     _Float16* __restrict__ outT,
                                     _Float16* __restrict__ outH,
                                     int R, int C, long sIn, long sOut) {
  __shared__ float t[32][33];
  const int b = blockIdx.z;
  const int c0 = blockIdx.x * 32, r0 = blockIdx.y * 32;
  const int tx = threadIdx.x & 31, ty = threadIdx.x >> 5;
  const float* ib = in + (size_t)b * sIn;
  _Float16* ob = outT + (size_t)b * sOut;
#pragma unroll
  for (int k = 0; k < 4; ++k) {
    float v = ib[(size_t)(r0 + ty + 8 * k) * C + c0 + tx];
    t[ty + 8 * k][tx] = v;
    if (outH)
      outH[(size_t)b * sOut + (size_t)(r0 + ty + 8 * k) * C + c0 + tx] = (_Float16)v;
  }
  __syncthreads();
#pragma unroll
  for (int k = 0; k < 4; ++k)
    ob[(size_t)(c0 + ty + 8 * k) * R + r0 + tx] = (_Float16)t[tx][ty + 8 * k];
}

// ---------------------------------------------------------------------------
// 128x128 4-wave MFMA GEMM, BK=32 — DEPTH-3 pipeline (T4 counted-vmcnt,
// 2 K-tiles of loads in flight; waits land on loads issued ~2 iters ago).
// Per-wave fragment/MFMA structure identical to the proven 2-phase kernel.
// LDS: 3 x (8KB A + 8KB B) = 48 KB -> 3 blocks/CU.
// Race-freedom: stage at iter t targets buf[(t+2)%3]; that buffer was last
// read at iter t-1 whose end-of-iter barrier all waves passed. Each wave
// waits its OWN tile-t loads (vmcnt(8/4/0)) before the barrier, so after
// the barrier all waves' tile-t loads are visible (proven discipline).
// TRI: upper-tri 6x6 128-tiling for symmetric output. nwg%8==0.
// ---------------------------------------------------------------------------
template<bool FP16OUT, bool BIAS, bool TRI>
__global__ __launch_bounds__(256) void gemm_bt_mfma(
    const _Float16* __restrict__ Ap, const _Float16* __restrict__ Bp,
    const float* __restrict__ bias, void* __restrict__ Cp,
    int K, int lda, int ldb, int ldc,
    long sA, long sB, long sC, int zdiv, long aCS, long bCS, long cCS,
    int gx, int gy) {
  __shared__ __align__(16) _Float16 ldsA[3][128 * 32];
  __shared__ __align__(16) _Float16 ldsB[3][128 * 32];

  const int nwg = gridDim.x;
  const int lid = blockIdx.x;
  const int wg = (lid & 7) * (nwg >> 3) + (lid >> 3);
  int bx, by, z;
  if constexpr (TRI) {
    int tt = wg % 21; z = wg / 21;
    int ti = 0, rem = tt;
    while (rem >= 6 - ti) { rem -= 6 - ti; ++ti; }
    by = ti; bx = ti + rem;
  } else {
    bx = wg % gx; int r2 = wg / gx; by = r2 % gy; z = r2 / gy;
  }
  const int bat = z % zdiv, chk = z / zdiv;
  const _Float16* A = Ap + (size_t)bat * sA + (size_t)chk * aCS;
  const _Float16* B = Bp + (size_t)bat * sB + (size_t)chk * bCS;
  const size_t cOff = (size_t)bat * sC + (size_t)chk * cCS;

  const int row0 = by * 128, col0 = bx * 128;
  const int tid = threadIdx.x;
  const int l = tid & 63, w = tid >> 6;
  const int lo = l & 15, hi = l >> 4;
  const int wr = w >> 1, wc = w & 1;
  const int rw = 32 * w;
  const int lr = l >> 2;
  const int ls = l & 3;

  f32x4 acc[4][4];
#pragma unroll
  for (int i = 0; i < 4; ++i)
#pragma unroll
    for (int j = 0; j < 4; ++j)
      acc[i][j] = (f32x4){0.f, 0.f, 0.f, 0.f};

  auto STAGE = [&](int hb, int k0) {
#pragma unroll
    for (int q = 0; q < 2; ++q) {
      const int r = rw + 16 * q + lr;
      const int ck = ls ^ ((r >> 1) & 3);
      gload16(A + (size_t)(row0 + r) * lda + k0 + 8 * ck,
              &ldsA[hb][(rw + 16 * q) * 32]);
      gload16(B + (size_t)(col0 + r) * ldb + k0 + 8 * ck,
              &ldsB[hb][(rw + 16 * q) * 32]);
    }
  };

  const int nt = K / 32;
  STAGE(0, 0);
  if (nt > 1) STAGE(1, 32);
  int cur = 0;
  for (int t = 0; t < nt; ++t) {
    // stage tile t+2 into buf (cur+2)%3 (last read at iter t-1; safe)
    if (t + 2 < nt) {
      int n2 = cur + 2; if (n2 >= 3) n2 -= 3;
      STAGE(n2, 32 * (t + 2));
      asm volatile("s_waitcnt vmcnt(8)" ::: "memory");   // tile t done
    } else if (t + 1 < nt) {
      asm volatile("s_waitcnt vmcnt(4)" ::: "memory");
    } else {
      asm volatile("s_waitcnt vmcnt(0)" ::: "memory");
    }
    __builtin_amdgcn_s_barrier();

    f16x8 a[4], b[4];
#pragma unroll
    for (int mi = 0; mi < 4; ++mi) {
      int Ra = 64 * wr + 16 * mi + lo;
      a[mi] = *(const f16x8*)&ldsA[cur][Ra * 32 + (hi ^ ((Ra >> 1) & 3)) * 8];
    }
#pragma unroll
    for (int ni = 0; ni < 4; ++ni) {
      int Rb = 64 * wc + 16 * ni + lo;
      b[ni] = *(const f16x8*)&ldsB[cur][Rb * 32 + (hi ^ ((Rb >> 1) & 3)) * 8];
    }
#pragma unroll
    for (int mi = 0; mi < 4; ++mi)
#pragma unroll
      for (int ni = 0; ni < 4; ++ni)
        acc[mi][ni] = __builtin_amdgcn_mfma_f32_16x16x32_f16(
            a[mi], b[ni], acc[mi][ni], 0, 0, 0);

    __builtin_amdgcn_s_barrier();   // all reads of buf cur done
    ++cur; if (cur == 3) cur = 0;
  }

#pragma unroll
  for (int ni = 0; ni < 4; ++ni) {
    const int col = col0 + 64 * wc + 16 * ni + lo;
    float bv = 0.f;
    if constexpr (BIAS) bv = bias[col];
#pragma unroll
    for (int mi = 0; mi < 4; ++mi) {
      const int rowb = row0 + 64 * wr + 16 * mi + 4 * hi;
#pragma unroll
      for (int r = 0; r < 4; ++r) {
        float v = acc[mi][ni][r] + bv;
        if constexpr (FP16OUT)
          ((_Float16*)Cp)[cOff + (size_t)(rowb + r) * ldc + col] = (_Float16)v;
        else
          ((float*)Cp)[cOff + (size_t)(rowb + r) * ldc + col] = v;
      }
    }
  }
}

// ---------------------------------------------------------------------------
// Reduce 4 split-K chunks of the 21 upper-tri 128-tiles and mirror to full G.
// grid (21, 8), block 256.
// ---------------------------------------------------------------------------
__global__ void reduce_mirror_kernel(const _Float16* __restrict__ GP,
                                     _Float16* __restrict__ G) {
  const int t = blockIdx.x, b = blockIdx.y;
  int ti = 0, rem = t;
  while (rem >= 6 - ti) { rem -= 6 - ti; ++ti; }
  const int tj = ti + rem;
  const int i0 = ti * 128, j0 = tj * 128;
  const int tx = threadIdx.x & 31, ty = threadIdx.x >> 5;
  __shared__ float lds[32][33];
  const size_t cs = (size_t)NB * CH * CH;
  const _Float16* gp = GP + (size_t)b * CH * CH;
  _Float16* g = G + (size_t)b * CH * CH;

  for (int st = 0; st < 16; ++st) {
    const int sr = i0 + (st >> 2) * 32, sc = j0 + (st & 3) * 32;
    __syncthreads();
#pragma unroll
    for (int k = 0; k < 4; ++k) {
      const int r = ty + 8 * k;
      const size_t off = (size_t)(sr + r) * CH + sc + tx;
      float v = ((float)gp[off] + (float)gp[cs + off]) +
                ((float)gp[2 * cs + off] + (float)gp[3 * cs + off]);
      lds[r][tx] = v;
      g[off] = (_Float16)v;
    }
    if (ti != tj) {
      __syncthreads();
#pragma unroll
      for (int k = 0; k < 4; ++k) {
        const int r = ty + 8 * k;
        g[(size_t)(sc + r) * CH + sr + tx] = (_Float16)lds[tx][r];
      }
    }
  }
}

// ---------------------------------------------------------------------------
// Norms: INV[t*8+b][c] = 1/max(sqrt(sum_i Ut[t][b][c][i]*Wt[t*768+c][i]),eps)
// ---------------------------------------------------------------------------
__global__ void norm_kernel(const _Float16* __restrict__ Ut,
                            const _Float16* __restrict__ Wt,
                            float* __restrict__ INVv) {
  const int z = blockIdx.x;
  const int t = z >> 3;
  const int c = blockIdx.y * 128 + threadIdx.x;
  const _Float16* u = Ut + ((size_t)z * CH + c) * CH;
  const _Float16* wv = Wt + ((size_t)(t * CH + c)) * CH;
  float s = 0.f;
  for (int i = 0; i < CH; i += 8) {
    f16x8 uv = *(const f16x8*)(u + i);
    f16x8 wq = *(const f16x8*)(wv + i);
#pragma unroll
    for (int q = 0; q < 8; ++q) s += (float)uv[q] * (float)wq[q];
  }
  s = fmaxf(s, 0.f);
  INVv[(size_t)z * CH + c] = 1.0f / fmaxf(sqrtf(s), 1e-12f);
}

// ---------------------------------------------------------------------------
// Fused S = Wq-rows . Ut1-rows^T (96x96, K=768) via MFMA, scale, softmax
// over e, transposed fp16 ATt write. grid 64 (bh), 256 threads.
// ---------------------------------------------------------------------------
__global__ __launch_bounds__(256) void sattn_kernel(
    const _Float16* __restrict__ WT_, const _Float16* __restrict__ UT_,
    const float* __restrict__ INVv, const float* __restrict__ temp,
    _Float16* __restrict__ ATt) {
  const int bh = blockIdx.x;
  const int b = bh >> 3, h = bh & 7;
  __shared__ __align__(16) _Float16 lds[2][192 * 32];
  __shared__ float S[96][100];

  const int tid = threadIdx.x;
  const int l = tid & 63, w = tid >> 6;
  const int lo = l & 15, hi = l >> 4;
  const int wr = w >> 1, wc = w & 1;
  const int lr = l >> 2, lq = l & 3;

  const _Float16* Abase = WT_ + (size_t)(h * HD) * CH;
  const _Float16* Bbase = UT_ + ((size_t)(8 + b) * CH + h * HD) * CH;

  f32x4 acc[3][3];
#pragma unroll
  for (int i = 0; i < 3; ++i)
#pragma unroll
    for (int j = 0; j < 3; ++j)
      acc[i][j] = (f32x4){0.f, 0.f, 0.f, 0.f};

  auto STAGE = [&](int hb, int k0) {
#pragma unroll
    for (int c = 0; c < 3; ++c) {
      const int group = w * 3 + c;
      const int row = group * 16 + lr;
      const int ck = lq ^ ((row >> 1) & 3);
      const _Float16* src = (row < 96)
          ? Abase + (size_t)row * CH + k0 + 8 * ck
          : Bbase + (size_t)(row - 96) * CH + k0 + 8 * ck;
      gload16(src, &lds[hb][group * 512]);
    }
  };

  STAGE(0, 0);
  int cur = 0;
  for (int t = 0; t < 24; ++t) {
    if (t + 1 < 24) {
      STAGE(cur ^ 1, 32 * (t + 1));
      asm volatile("s_waitcnt vmcnt(3)" ::: "memory");
    } else {
      asm volatile("s_waitcnt vmcnt(0)" ::: "memory");
    }
    __builtin_amdgcn_s_barrier();

    f16x8 a[3], bb[3];
#pragma unroll
    for (int mi = 0; mi < 3; ++mi) {
      const int Ra = 48 * wr + 16 * mi + lo;
      a[mi] = *(const f16x8*)&lds[cur][Ra * 32 + (hi ^ ((Ra >> 1) & 3)) * 8];
    }
#pragma unroll
    for (int ni = 0; ni < 3; ++ni) {
      const int Rb = 96 + 48 * wc + 16 * ni + lo;
      bb[ni] = *(const f16x8*)&lds[cur][Rb * 32 + (hi ^ ((Rb >> 1) & 3)) * 8];
    }
#pragma unroll
    for (int mi = 0; mi < 3; ++mi)
#pragma unroll
      for (int ni = 0; ni < 3; ++ni)
        acc[mi][ni] = __builtin_amdgcn_mfma_f32_16x16x32_f16(
            a[mi], bb[ni], acc[mi][ni], 0, 0, 0);

    __builtin_amdgcn_s_barrier();
    cur ^= 1;
  }

  const float tv = temp[h];
  const float* iq = INVv + (size_t)b * CH + h * HD;
  const float* ik = INVv + (size_t)(8 + b) * CH + h * HD;
#pragma unroll
  for (int ni = 0; ni < 3; ++ni) {
    const int col = 48 * wc + 16 * ni + lo;
    const float ikv = ik[col];
#pragma unroll
    for (int mi = 0; mi < 3; ++mi) {
      const int rb = 48 * wr + 16 * mi + 4 * hi;
#pragma unroll
      for (int r = 0; r < 4; ++r)
        S[rb + r][col] = acc[mi][ni][r] * iq[rb + r] * ikv * tv;
    }
  }
  __syncthreads();

  const int g16 = tid >> 4, l16 = tid & 15;
  _Float16* ab = ATt + (size_t)bh * 9216;
#pragma unroll
  for (int it = 0; it < 6; ++it) {
    const int d = g16 + 16 * it;
    float v[6];
    float mx = -INFINITY;
#pragma unroll
    for (int j = 0; j < 6; ++j) { v[j] = S[d][l16 * 6 + j]; mx = fmaxf(mx, v[j]); }
#pragma unroll
    for (int m = 1; m < 16; m <<= 1) mx = fmaxf(mx, __shfl_xor(mx, m, 16));
    float sum = 0.f;
#pragma unroll
    for (int j = 0; j < 6; ++j) { v[j] = __expf(v[j] - mx); sum += v[j]; }
#pragma unroll
    for (int m = 1; m < 16; m <<= 1) sum += __shfl_xor(sum, m, 16);
    const float inv = 1.0f / sum;
#pragma unroll
    for (int j = 0; j < 6; ++j)
      ab[(size_t)(l16 * 6 + j) * 96 + d] = (_Float16)(v[j] * inv);
  }
}

// ---------------------------------------------------------------------------
// Mt[b][j][h*96+e] = sum_d Wpt[j][h96+d] * ATt[bh][e][d]
// ---------------------------------------------------------------------------
__global__ void mt_kernel(const _Float16* __restrict__ Wpt,
                          const _Float16* __restrict__ ATt,
                          _Float16* __restrict__ Mt) {
  const int j0 = blockIdx.x * 128;
  const int bh = blockIdx.y;
  const int b = bh >> 3, h = bh & 7;
  const int tx = threadIdx.x & 15, ty = threadIdx.x >> 4;
  __shared__ float Ws[16][128], Ats[16][96];
  float acc[8][6] = {};

  for (int d0 = 0; d0 < 96; d0 += 16) {
    {
      int jj = threadIdx.x >> 1, s8 = (threadIdx.x & 1) * 8;
      f16x8 v = *(const f16x8*)(Wpt + (size_t)(j0 + jj) * CH + h * HD + d0 + s8);
#pragma unroll
      for (int q = 0; q < 8; ++q) Ws[s8 + q][jj] = (float)v[q];
    }
    if (threadIdx.x < 192) {
      int e = threadIdx.x >> 1, s8 = (threadIdx.x & 1) * 8;
      f16x8 v = *(const f16x8*)(ATt + (size_t)bh * 9216 + (size_t)e * 96 + d0 + s8);
#pragma unroll
      for (int q = 0; q < 8; ++q) Ats[s8 + q][e] = (float)v[q];
    }
    __syncthreads();
#pragma unroll
    for (int kk = 0; kk < 16; ++kk) {
      float a[8], bb[6];
#pragma unroll
      for (int i = 0; i < 8; ++i) a[i] = Ws[kk][ty * 8 + i];
#pragma unroll
      for (int j = 0; j < 6; ++j) bb[j] = Ats[kk][tx * 6 + j];
#pragma unroll
      for (int i = 0; i < 8; ++i)
#pragma unroll
        for (int j = 0; j < 6; ++j)
          acc[i][j] += a[i] * bb[j];
    }
    __syncthreads();
  }

  _Float16* mb = Mt + (size_t)b * CH * CH;
#pragma unroll
  for (int i = 0; i < 8; ++i)
#pragma unroll
    for (int j = 0; j < 6; ++j)
      mb[(size_t)(j0 + ty * 8 + i) * CH + h * HD + tx * 6 + j] = (_Float16)acc[i][j];
}

// ---------------------------------------------------------------------------
extern "C" void kernel_launch(void* const* d_in, const int* in_sizes, int n_in,
                              void* d_out, int out_size, void* d_ws, size_t ws_size,
                              hipStream_t stream) {
  const float* x      = (const float*)d_in[0];
  const float* W_qkv  = (const float*)d_in[1];
  const float* W_proj = (const float*)d_in[2];
  const float* b_proj = (const float*)d_in[3];
  const float* temp   = (const float*)d_in[4];
  float* out = (float*)d_out;
  char* ws = (char*)d_ws;

  _Float16* XT  = (_Float16*)(ws + XT_B);
  _Float16* UT  = (_Float16*)(ws + UT_B);
  _Float16* ATT = (_Float16*)(ws + ATT_B);
  _Float16* MT  = (_Float16*)(ws + MT_B);
  _Float16* PT  = (_Float16*)(ws + PT_B);
  _Float16* GP  = (_Float16*)(ws + GP_B);
  _Float16* XH  = (_Float16*)(ws + XH_B);
  _Float16* WH  = (_Float16*)(ws + WH_B);
  _Float16* WT  = (_Float16*)(ws + WT_B);
  _Float16* WPT = (_Float16*)(ws + WPT_B);
  _Float16* G   = (_Float16*)(ws + G_B);
  float*    INV = (float*)   (ws + INV_B);

  const bool fast = ws_size >= XH2_B + XH_BYTES;   // 168.7 MB
  _Float16* XHU = fast ? (_Float16*)(ws + XH2_B) : XH;

  const long CC = (long)CH * CH;           // 589824
  const long SC = (long)SEQ * CH;          // 3145728

  // --- weight converts / transposes; x -> XT (+XH if fast) ---
  cvt_f16_kernel<<<(CH * NC3 / 4 + 255) / 256, 256, 0, stream>>>(
      W_qkv, WH, CH * NC3 / 4);
  transpose_cvt_kernel<<<dim3(CH / 32, SEQ / 32, NB), 256, 0, stream>>>(
      x, XT, fast ? XHU : nullptr, SEQ, CH, SC, SC);
  transpose_cvt_kernel<<<dim3(NC3 / 32, CH / 32, 1), 256, 0, stream>>>(
      W_qkv, WT, nullptr, CH, NC3, 0, 0);
  transpose_cvt_kernel<<<dim3(CH / 32, CH / 32, 1), 256, 0, stream>>>(
      W_proj, WPT, nullptr, CH, CH, 0, 0);

  // --- G upper-tri partials: 21 tiles x (8 b x 4 K-chunks) = 672 blocks ---
  gemm_bt_mfma<true, false, true><<<672, 256, 0, stream>>>(
      XT, XT, nullptr, GP, 1024, SEQ, SEQ, CH,
      (long)CH * SEQ, (long)CH * SEQ, CC, NB, 1024, 1024, (long)NB * CC,
      21, 1);

  // --- reduce chunks + mirror to full symmetric G ---
  reduce_mirror_kernel<<<dim3(21, NB), 256, 0, stream>>>(GP, G);

  // --- U fused over t: UT[t][b] = Wt_t . G_b^T  (z = t*8+b), 576 blocks ---
  gemm_bt_mfma<true, false, false><<<576, 256, 0, stream>>>(
      WT, G, nullptr, UT, CH, CH, CH, CH,
      0, CC, CC, NB, CC, 0, (long)NB * CC, 6, 6);

  // --- norms ---
  norm_kernel<<<dim3(16, 6), 128, 0, stream>>>(UT, WT, INV);

  // --- fused S + scale + softmax -> ATt ---
  sattn_kernel<<<64, 256, 0, stream>>>(WT, UT, INV, temp, ATT);

  // --- Mt ---
  mt_kernel<<<dim3(6, 64), 256, 0, stream>>>(WPT, ATT, MT);

  // --- Pt_b = Mt_b . Wv^T (288 blocks) ---
  gemm_bt_mfma<true, false, false><<<288, 256, 0, stream>>>(
      MT, WH + 2 * CH, nullptr, PT, CH, CH, NC3, CH,
      CC, 0, CC, NB, 0, 0, 0, 6, 6);

  // --- fallback: x -> XH (GP dead after reduce_mirror) ---
  if (!fast)
    cvt_f16_kernel<<<(int)(NB * SC / 4 / 256), 256, 0, stream>>>(
        x, XH, (int)(NB * SC / 4));

  // --- out_b = XH_b . Pt_b^T + bias  (M=4096, N=768, K=768), 1536 blocks ---
  gemm_bt_mfma<false, true, false><<<1536, 256, 0, stream>>>(
      XHU, PT, b_proj, out, CH, CH, CH, CH,
      SC, CC, SC, NB, 0, 0, 0, 6, 32);
}

// Round 11
// 265.367 us; speedup vs baseline: 1.1765x; 1.0059x over previous
//
#include <hip/hip_runtime.h>
#include <math.h>

// Problem constants (b=8, n=4096, c=768, h=8, d=96)
#define NB  8
#define SEQ 4096
#define CH  768
#define NH  8
#define HD  96
#define NC3 2304   // 3*CH

typedef _Float16 f16x8 __attribute__((ext_vector_type(8)));
typedef _Float16 f16x4 __attribute__((ext_vector_type(4)));
typedef float    f32x4 __attribute__((ext_vector_type(4)));

// ---------------------------------------------------------------------------
// Workspace layout (BYTE offsets). Base = 118,407,168 B (proven). Optional
// XH2 (fp16 x row-major) appended if ws_size >= 168,738,816.
// ---------------------------------------------------------------------------
static const size_t XT_B   = 0;           // fp16 x^T [b][c][n]; dies after G
static const size_t UT_B   = 0;           // overlays XT
static const size_t ATT_B  = 28311552;
static const size_t MT_B   = 29491200;
static const size_t PT_B   = 38928384;
static const size_t GP_B   = 50331648;    // G partials; dies after reduce
static const size_t XH_B   = 50331648;    // fallback XH (fills after reduce)
static const size_t WH_B   = 100663296;
static const size_t WT_B   = 104202240;
static const size_t WPT_B  = 107741184;
static const size_t G_B    = 108920832;
static const size_t INV_B  = 118358016;
static const size_t XH2_B  = 118407168;   // fast-path XH (needs big ws)
static const size_t XH_BYTES = (size_t)NB * SEQ * CH * 2;   // 50,331,648

// ---------------------------------------------------------------------------
// async global->LDS, 16 B per lane (wave-uniform LDS base + lane*16)
// ---------------------------------------------------------------------------
__device__ __forceinline__ void gload16(const void* g, void* l) {
  __builtin_amdgcn_global_load_lds(
      (const __attribute__((address_space(1))) void*)g,
      (__attribute__((address_space(3))) void*)l, 16, 0, 0);
}

// ---------------------------------------------------------------------------
// Elementwise fp32 -> fp16 convert (fallback XH path only)
// ---------------------------------------------------------------------------
__global__ void cvt_f16_kernel(const float* __restrict__ in,
                               _Float16* __restrict__ out, int n4) {
  int i = blockIdx.x * blockDim.x + threadIdx.x;
  if (i < n4) {
    float4 v = *(const float4*)(in + (size_t)i * 4);
    _Float16* o = out + (size_t)i * 4;
    o[0] = (_Float16)v.x; o[1] = (_Float16)v.y;
    o[2] = (_Float16)v.z; o[3] = (_Float16)v.w;
  }
}

// ---------------------------------------------------------------------------
// Vectorized 64x64 transpose+convert: fp32 [R][C] -> fp16 [C][R] (outT, 16B
// stores via LDS), optional fp16 [R][C] (outH, 8B stores). grid (C/64, R/64,
// batch), 256 threads. Load: float4; LDS [64][68] f32 (16B-aligned rows).
// ---------------------------------------------------------------------------
__global__ __launch_bounds__(256) void transpose64_kernel(
    const float* __restrict__ in, _Float16* __restrict__ outT,
    _Float16* __restrict__ outH, int R, int C, long sIn, long sOut) {
  __shared__ __align__(16) float ts[64][68];
  const int b = blockIdx.z;
  const int c0 = blockIdx.x * 64, r0 = blockIdx.y * 64;
  const float* ib = in + (size_t)b * sIn;

  const int c4 = (threadIdx.x & 15) * 4;      // col within tile, x4
  const int rr = threadIdx.x >> 4;            // 0..15
#pragma unroll
  for (int q = 0; q < 4; ++q) {
    const int row = rr + 16 * q;
    float4 v = *(const float4*)&ib[(size_t)(r0 + row) * C + c0 + c4];
    *(float4*)&ts[row][c4] = v;
    if (outH) {
      f16x4 h = {(_Float16)v.x, (_Float16)v.y, (_Float16)v.z, (_Float16)v.w};
      *(f16x4*)&outH[(size_t)b * sOut + (size_t)(r0 + row) * C + c0 + c4] = h;
    }
  }
  __syncthreads();

  // transposed write: thread covers col (t>>2), 16 n at nseg=(t&3)*16
  const int col = threadIdx.x >> 2;
  const int nseg = (threadIdx.x & 3) * 16;
  _Float16* ob = outT + (size_t)b * sOut + (size_t)(c0 + col) * R + r0 + nseg;
#pragma unroll
  for (int half = 0; half < 2; ++half) {
    f16x8 h;
#pragma unroll
    for (int j = 0; j < 8; ++j)
      h[j] = (_Float16)ts[nseg + half * 8 + j][col];
    *(f16x8*)&ob[half * 8] = h;
  }
}

// ---------------------------------------------------------------------------
// 128x128 4-wave MFMA GEMM, BK=32 — depth-3 counted-vmcnt pipeline (r10).
// fp32 epilogue repacked through per-wave LDS scratch -> float4 C stores.
// TRI: upper-tri 6x6 128-tiling for symmetric output. nwg%8==0.
// ---------------------------------------------------------------------------
template<bool FP16OUT, bool BIAS, bool TRI>
__global__ __launch_bounds__(256) void gemm_bt_mfma(
    const _Float16* __restrict__ Ap, const _Float16* __restrict__ Bp,
    const float* __restrict__ bias, void* __restrict__ Cp,
    int K, int lda, int ldb, int ldc,
    long sA, long sB, long sC, int zdiv, long aCS, long bCS, long cCS,
    int gx, int gy) {
  __shared__ __align__(16) _Float16 ldsA[3][128 * 32];
  __shared__ __align__(16) _Float16 ldsB[3][128 * 32];

  const int nwg = gridDim.x;
  const int lid = blockIdx.x;
  const int wg = (lid & 7) * (nwg >> 3) + (lid >> 3);
  int bx, by, z;
  if constexpr (TRI) {
    int tt = wg % 21; z = wg / 21;
    int ti = 0, rem = tt;
    while (rem >= 6 - ti) { rem -= 6 - ti; ++ti; }
    by = ti; bx = ti + rem;
  } else {
    bx = wg % gx; int r2 = wg / gx; by = r2 % gy; z = r2 / gy;
  }
  const int bat = z % zdiv, chk = z / zdiv;
  const _Float16* A = Ap + (size_t)bat * sA + (size_t)chk * aCS;
  const _Float16* B = Bp + (size_t)bat * sB + (size_t)chk * bCS;
  const size_t cOff = (size_t)bat * sC + (size_t)chk * cCS;

  const int row0 = by * 128, col0 = bx * 128;
  const int tid = threadIdx.x;
  const int l = tid & 63, w = tid >> 6;
  const int lo = l & 15, hi = l >> 4;
  const int wr = w >> 1, wc = w & 1;
  const int rw = 32 * w;
  const int lr = l >> 2;
  const int ls = l & 3;

  f32x4 acc[4][4];
#pragma unroll
  for (int i = 0; i < 4; ++i)
#pragma unroll
    for (int j = 0; j < 4; ++j)
      acc[i][j] = (f32x4){0.f, 0.f, 0.f, 0.f};

  auto STAGE = [&](int hb, int k0) {
#pragma unroll
    for (int q = 0; q < 2; ++q) {
      const int r = rw + 16 * q + lr;
      const int ck = ls ^ ((r >> 1) & 3);
      gload16(A + (size_t)(row0 + r) * lda + k0 + 8 * ck,
              &ldsA[hb][(rw + 16 * q) * 32]);
      gload16(B + (size_t)(col0 + r) * ldb + k0 + 8 * ck,
              &ldsB[hb][(rw + 16 * q) * 32]);
    }
  };

  const int nt = K / 32;
  STAGE(0, 0);
  if (nt > 1) STAGE(1, 32);
  int cur = 0;
  for (int t = 0; t < nt; ++t) {
    if (t + 2 < nt) {
      int n2 = cur + 2; if (n2 >= 3) n2 -= 3;
      STAGE(n2, 32 * (t + 2));
      asm volatile("s_waitcnt vmcnt(8)" ::: "memory");   // tile t done
    } else if (t + 1 < nt) {
      asm volatile("s_waitcnt vmcnt(4)" ::: "memory");
    } else {
      asm volatile("s_waitcnt vmcnt(0)" ::: "memory");
    }
    __builtin_amdgcn_s_barrier();

    f16x8 a[4], b[4];
#pragma unroll
    for (int mi = 0; mi < 4; ++mi) {
      int Ra = 64 * wr + 16 * mi + lo;
      a[mi] = *(const f16x8*)&ldsA[cur][Ra * 32 + (hi ^ ((Ra >> 1) & 3)) * 8];
    }
#pragma unroll
    for (int ni = 0; ni < 4; ++ni) {
      int Rb = 64 * wc + 16 * ni + lo;
      b[ni] = *(const f16x8*)&ldsB[cur][Rb * 32 + (hi ^ ((Rb >> 1) & 3)) * 8];
    }
#pragma unroll
    for (int mi = 0; mi < 4; ++mi)
#pragma unroll
      for (int ni = 0; ni < 4; ++ni)
        acc[mi][ni] = __builtin_amdgcn_mfma_f32_16x16x32_f16(
            a[mi], b[ni], acc[mi][ni], 0, 0, 0);

    __builtin_amdgcn_s_barrier();   // all reads of buf cur done
    ++cur; if (cur == 3) cur = 0;
  }

  if constexpr (!FP16OUT) {
    // fp32 epilogue: scatter to per-wave LDS (stride 68, 16B-aligned rows),
    // gather float4 -> vectorized C stores. Per-wave region: 1088 f32.
    float* smw = (float*)&ldsA[0][0] + w * 1088;
    float* Cb = (float*)Cp + cOff;
    float bv[4];
#pragma unroll
    for (int ni = 0; ni < 4; ++ni)
      bv[ni] = BIAS ? bias[col0 + 64 * wc + 16 * ni + lo] : 0.f;
    const int grow = l & 15, gseg = l >> 4;
#pragma unroll
    for (int mi = 0; mi < 4; ++mi) {
#pragma unroll
      for (int ni = 0; ni < 4; ++ni)
#pragma unroll
        for (int r = 0; r < 4; ++r)
          smw[(4 * hi + r) * 68 + 16 * ni + lo] = acc[mi][ni][r] + bv[ni];
      // per-wave in-order LDS; compiler inserts lgkmcnt for the RAW dep
#pragma unroll
      for (int j = 0; j < 4; ++j) {
        float4 v = *(const float4*)&smw[grow * 68 + gseg * 16 + 4 * j];
        *(float4*)&Cb[(size_t)(row0 + 64 * wr + 16 * mi + grow) * ldc
                      + col0 + 64 * wc + gseg * 16 + 4 * j] = v;
      }
    }
  } else {
#pragma unroll
    for (int ni = 0; ni < 4; ++ni) {
      const int col = col0 + 64 * wc + 16 * ni + lo;
      float bv = 0.f;
      if constexpr (BIAS) bv = bias[col];
#pragma unroll
      for (int mi = 0; mi < 4; ++mi) {
        const int rowb = row0 + 64 * wr + 16 * mi + 4 * hi;
#pragma unroll
        for (int r = 0; r < 4; ++r)
          ((_Float16*)Cp)[cOff + (size_t)(rowb + r) * ldc + col] =
              (_Float16)(acc[mi][ni][r] + bv);
      }
    }
  }
}

// ---------------------------------------------------------------------------
// Reduce 4 split-K chunks of the 21 upper-tri 128-tiles and mirror to full G.
// grid (21, 8), block 256.
// ---------------------------------------------------------------------------
__global__ void reduce_mirror_kernel(const _Float16* __restrict__ GP,
                                     _Float16* __restrict__ G) {
  const int t = blockIdx.x, b = blockIdx.y;
  int ti = 0, rem = t;
  while (rem >= 6 - ti) { rem -= 6 - ti; ++ti; }
  const int tj = ti + rem;
  const int i0 = ti * 128, j0 = tj * 128;
  const int tx = threadIdx.x & 31, ty = threadIdx.x >> 5;
  __shared__ float lds[32][33];
  const size_t cs = (size_t)NB * CH * CH;
  const _Float16* gp = GP + (size_t)b * CH * CH;
  _Float16* g = G + (size_t)b * CH * CH;

  for (int st = 0; st < 16; ++st) {
    const int sr = i0 + (st >> 2) * 32, sc = j0 + (st & 3) * 32;
    __syncthreads();
#pragma unroll
    for (int k = 0; k < 4; ++k) {
      const int r = ty + 8 * k;
      const size_t off = (size_t)(sr + r) * CH + sc + tx;
      float v = ((float)gp[off] + (float)gp[cs + off]) +
                ((float)gp[2 * cs + off] + (float)gp[3 * cs + off]);
      lds[r][tx] = v;
      g[off] = (_Float16)v;
    }
    if (ti != tj) {
      __syncthreads();
#pragma unroll
      for (int k = 0; k < 4; ++k) {
        const int r = ty + 8 * k;
        g[(size_t)(sc + r) * CH + sr + tx] = (_Float16)lds[tx][r];
      }
    }
  }
}

// ---------------------------------------------------------------------------
// Norms: INV[t*8+b][c] = 1/max(sqrt(sum_i Ut[t][b][c][i]*Wt[t*768+c][i]),eps)
// ---------------------------------------------------------------------------
__global__ void norm_kernel(const _Float16* __restrict__ Ut,
                            const _Float16* __restrict__ Wt,
                            float* __restrict__ INVv) {
  const int z = blockIdx.x;
  const int t = z >> 3;
  const int c = blockIdx.y * 128 + threadIdx.x;
  const _Float16* u = Ut + ((size_t)z * CH + c) * CH;
  const _Float16* wv = Wt + ((size_t)(t * CH + c)) * CH;
  float s = 0.f;
  for (int i = 0; i < CH; i += 8) {
    f16x8 uv = *(const f16x8*)(u + i);
    f16x8 wq = *(const f16x8*)(wv + i);
#pragma unroll
    for (int q = 0; q < 8; ++q) s += (float)uv[q] * (float)wq[q];
  }
  s = fmaxf(s, 0.f);
  INVv[(size_t)z * CH + c] = 1.0f / fmaxf(sqrtf(s), 1e-12f);
}

// ---------------------------------------------------------------------------
// Fused S = Wq-rows . Ut1-rows^T (96x96, K=768) via MFMA, scale, softmax
// over e, transposed fp16 ATt write. grid 64 (bh), 256 threads.
// ---------------------------------------------------------------------------
__global__ __launch_bounds__(256) void sattn_kernel(
    const _Float16* __restrict__ WT_, const _Float16* __restrict__ UT_,
    const float* __restrict__ INVv, const float* __restrict__ temp,
    _Float16* __restrict__ ATt) {
  const int bh = blockIdx.x;
  const int b = bh >> 3, h = bh & 7;
  __shared__ __align__(16) _Float16 lds[2][192 * 32];
  __shared__ float S[96][100];

  const int tid = threadIdx.x;
  const int l = tid & 63, w = tid >> 6;
  const int lo = l & 15, hi = l >> 4;
  const int wr = w >> 1, wc = w & 1;
  const int lr = l >> 2, lq = l & 3;

  const _Float16* Abase = WT_ + (size_t)(h * HD) * CH;
  const _Float16* Bbase = UT_ + ((size_t)(8 + b) * CH + h * HD) * CH;

  f32x4 acc[3][3];
#pragma unroll
  for (int i = 0; i < 3; ++i)
#pragma unroll
    for (int j = 0; j < 3; ++j)
      acc[i][j] = (f32x4){0.f, 0.f, 0.f, 0.f};

  auto STAGE = [&](int hb, int k0) {
#pragma unroll
    for (int c = 0; c < 3; ++c) {
      const int group = w * 3 + c;
      const int row = group * 16 + lr;
      const int ck = lq ^ ((row >> 1) & 3);
      const _Float16* src = (row < 96)
          ? Abase + (size_t)row * CH + k0 + 8 * ck
          : Bbase + (size_t)(row - 96) * CH + k0 + 8 * ck;
      gload16(src, &lds[hb][group * 512]);
    }
  };

  STAGE(0, 0);
  int cur = 0;
  for (int t = 0; t < 24; ++t) {
    if (t + 1 < 24) {
      STAGE(cur ^ 1, 32 * (t + 1));
      asm volatile("s_waitcnt vmcnt(3)" ::: "memory");
    } else {
      asm volatile("s_waitcnt vmcnt(0)" ::: "memory");
    }
    __builtin_amdgcn_s_barrier();

    f16x8 a[3], bb[3];
#pragma unroll
    for (int mi = 0; mi < 3; ++mi) {
      const int Ra = 48 * wr + 16 * mi + lo;
      a[mi] = *(const f16x8*)&lds[cur][Ra * 32 + (hi ^ ((Ra >> 1) & 3)) * 8];
    }
#pragma unroll
    for (int ni = 0; ni < 3; ++ni) {
      const int Rb = 96 + 48 * wc + 16 * ni + lo;
      bb[ni] = *(const f16x8*)&lds[cur][Rb * 32 + (hi ^ ((Rb >> 1) & 3)) * 8];
    }
#pragma unroll
    for (int mi = 0; mi < 3; ++mi)
#pragma unroll
      for (int ni = 0; ni < 3; ++ni)
        acc[mi][ni] = __builtin_amdgcn_mfma_f32_16x16x32_f16(
            a[mi], bb[ni], acc[mi][ni], 0, 0, 0);

    __builtin_amdgcn_s_barrier();
    cur ^= 1;
  }

  const float tv = temp[h];
  const float* iq = INVv + (size_t)b * CH + h * HD;
  const float* ik = INVv + (size_t)(8 + b) * CH + h * HD;
#pragma unroll
  for (int ni = 0; ni < 3; ++ni) {
    const int col = 48 * wc + 16 * ni + lo;
    const float ikv = ik[col];
#pragma unroll
    for (int mi = 0; mi < 3; ++mi) {
      const int rb = 48 * wr + 16 * mi + 4 * hi;
#pragma unroll
      for (int r = 0; r < 4; ++r)
        S[rb + r][col] = acc[mi][ni][r] * iq[rb + r] * ikv * tv;
    }
  }
  __syncthreads();

  const int g16 = tid >> 4, l16 = tid & 15;
  _Float16* ab = ATt + (size_t)bh * 9216;
#pragma unroll
  for (int it = 0; it < 6; ++it) {
    const int d = g16 + 16 * it;
    float v[6];
    float mx = -INFINITY;
#pragma unroll
    for (int j = 0; j < 6; ++j) { v[j] = S[d][l16 * 6 + j]; mx = fmaxf(mx, v[j]); }
#pragma unroll
    for (int m = 1; m < 16; m <<= 1) mx = fmaxf(mx, __shfl_xor(mx, m, 16));
    float sum = 0.f;
#pragma unroll
    for (int j = 0; j < 6; ++j) { v[j] = __expf(v[j] - mx); sum += v[j]; }
#pragma unroll
    for (int m = 1; m < 16; m <<= 1) sum += __shfl_xor(sum, m, 16);
    const float inv = 1.0f / sum;
#pragma unroll
    for (int j = 0; j < 6; ++j)
      ab[(size_t)(l16 * 6 + j) * 96 + d] = (_Float16)(v[j] * inv);
  }
}

// ---------------------------------------------------------------------------
// Mt[b][j][h*96+e] = sum_d Wpt[j][h96+d] * ATt[bh][e][d]
// ---------------------------------------------------------------------------
__global__ void mt_kernel(const _Float16* __restrict__ Wpt,
                          const _Float16* __restrict__ ATt,
                          _Float16* __restrict__ Mt) {
  const int j0 = blockIdx.x * 128;
  const int bh = blockIdx.y;
  const int b = bh >> 3, h = bh & 7;
  const int tx = threadIdx.x & 15, ty = threadIdx.x >> 4;
  __shared__ float Ws[16][128], Ats[16][96];
  float acc[8][6] = {};

  for (int d0 = 0; d0 < 96; d0 += 16) {
    {
      int jj = threadIdx.x >> 1, s8 = (threadIdx.x & 1) * 8;
      f16x8 v = *(const f16x8*)(Wpt + (size_t)(j0 + jj) * CH + h * HD + d0 + s8);
#pragma unroll
      for (int q = 0; q < 8; ++q) Ws[s8 + q][jj] = (float)v[q];
    }
    if (threadIdx.x < 192) {
      int e = threadIdx.x >> 1, s8 = (threadIdx.x & 1) * 8;
      f16x8 v = *(const f16x8*)(ATt + (size_t)bh * 9216 + (size_t)e * 96 + d0 + s8);
#pragma unroll
      for (int q = 0; q < 8; ++q) Ats[s8 + q][e] = (float)v[q];
    }
    __syncthreads();
#pragma unroll
    for (int kk = 0; kk < 16; ++kk) {
      float a[8], bb[6];
#pragma unroll
      for (int i = 0; i < 8; ++i) a[i] = Ws[kk][ty * 8 + i];
#pragma unroll
      for (int j = 0; j < 6; ++j) bb[j] = Ats[kk][tx * 6 + j];
#pragma unroll
      for (int i = 0; i < 8; ++i)
#pragma unroll
        for (int j = 0; j < 6; ++j)
          acc[i][j] += a[i] * bb[j];
    }
    __syncthreads();
  }

  _Float16* mb = Mt + (size_t)b * CH * CH;
#pragma unroll
  for (int i = 0; i < 8; ++i)
#pragma unroll
    for (int j = 0; j < 6; ++j)
      mb[(size_t)(j0 + ty * 8 + i) * CH + h * HD + tx * 6 + j] = (_Float16)acc[i][j];
}

// ---------------------------------------------------------------------------
extern "C" void kernel_launch(void* const* d_in, const int* in_sizes, int n_in,
                              void* d_out, int out_size, void* d_ws, size_t ws_size,
                              hipStream_t stream) {
  const float* x      = (const float*)d_in[0];
  const float* W_qkv  = (const float*)d_in[1];
  const float* W_proj = (const float*)d_in[2];
  const float* b_proj = (const float*)d_in[3];
  const float* temp   = (const float*)d_in[4];
  float* out = (float*)d_out;
  char* ws = (char*)d_ws;

  _Float16* XT  = (_Float16*)(ws + XT_B);
  _Float16* UT  = (_Float16*)(ws + UT_B);
  _Float16* ATT = (_Float16*)(ws + ATT_B);
  _Float16* MT  = (_Float16*)(ws + MT_B);
  _Float16* PT  = (_Float16*)(ws + PT_B);
  _Float16* GP  = (_Float16*)(ws + GP_B);
  _Float16* XH  = (_Float16*)(ws + XH_B);
  _Float16* WH  = (_Float16*)(ws + WH_B);
  _Float16* WT  = (_Float16*)(ws + WT_B);
  _Float16* WPT = (_Float16*)(ws + WPT_B);
  _Float16* G   = (_Float16*)(ws + G_B);
  float*    INV = (float*)   (ws + INV_B);

  const bool fast = ws_size >= XH2_B + XH_BYTES;   // 168.7 MB
  _Float16* XHU = fast ? (_Float16*)(ws + XH2_B) : XH;

  const long CC = (long)CH * CH;           // 589824
  const long SC = (long)SEQ * CH;          // 3145728

  // --- transposes (vectorized); WH fused into the WT pass ---
  transpose64_kernel<<<dim3(CH / 64, SEQ / 64, NB), 256, 0, stream>>>(
      x, XT, fast ? XHU : nullptr, SEQ, CH, SC, SC);
  transpose64_kernel<<<dim3(NC3 / 64, CH / 64, 1), 256, 0, stream>>>(
      W_qkv, WT, WH, CH, NC3, 0, 0);
  transpose64_kernel<<<dim3(CH / 64, CH / 64, 1), 256, 0, stream>>>(
      W_proj, WPT, nullptr, CH, CH, 0, 0);

  // --- G upper-tri partials: 21 tiles x (8 b x 4 K-chunks) = 672 blocks ---
  gemm_bt_mfma<true, false, true><<<672, 256, 0, stream>>>(
      XT, XT, nullptr, GP, 1024, SEQ, SEQ, CH,
      (long)CH * SEQ, (long)CH * SEQ, CC, NB, 1024, 1024, (long)NB * CC,
      21, 1);

  // --- reduce chunks + mirror to full symmetric G ---
  reduce_mirror_kernel<<<dim3(21, NB), 256, 0, stream>>>(GP, G);

  // --- U fused over t: UT[t][b] = Wt_t . G_b^T  (z = t*8+b), 576 blocks ---
  gemm_bt_mfma<true, false, false><<<576, 256, 0, stream>>>(
      WT, G, nullptr, UT, CH, CH, CH, CH,
      0, CC, CC, NB, CC, 0, (long)NB * CC, 6, 6);

  // --- norms ---
  norm_kernel<<<dim3(16, 6), 128, 0, stream>>>(UT, WT, INV);

  // --- fused S + scale + softmax -> ATt ---
  sattn_kernel<<<64, 256, 0, stream>>>(WT, UT, INV, temp, ATT);

  // --- Mt ---
  mt_kernel<<<dim3(6, 64), 256, 0, stream>>>(WPT, ATT, MT);

  // --- Pt_b = Mt_b . Wv^T (288 blocks) ---
  gemm_bt_mfma<true, false, false><<<288, 256, 0, stream>>>(
      MT, WH + 2 * CH, nullptr, PT, CH, CH, NC3, CH,
      CC, 0, CC, NB, 0, 0, 0, 6, 6);

  // --- fallback: x -> XH (GP dead after reduce_mirror) ---
  if (!fast)
    cvt_f16_kernel<<<(int)(NB * SC / 4 / 256), 256, 0, stream>>>(
        x, XH, (int)(NB * SC / 4));

  // --- out_b = XH_b . Pt_b^T + bias  (M=4096, N=768, K=768), 1536 blocks ---
  gemm_bt_mfma<false, true, false><<<1536, 256, 0, stream>>>(
      XHU, PT, b_proj, out, CH, CH, CH, CH,
      SC, CC, SC, NB, 0, 0, 0, 6, 32);
}

// Round 12
// 249.466 us; speedup vs baseline: 1.2515x; 1.0637x over previous
//
#include <hip/hip_runtime.h>
#include <math.h>

// Problem constants (b=8, n=4096, c=768, h=8, d=96)
#define NB  8
#define SEQ 4096
#define CH  768
#define NH  8
#define HD  96
#define NC3 2304   // 3*CH

typedef _Float16 f16x8 __attribute__((ext_vector_type(8)));
typedef _Float16 f16x4 __attribute__((ext_vector_type(4)));
typedef float    f32x4 __attribute__((ext_vector_type(4)));

// ---------------------------------------------------------------------------
// Workspace layout (BYTE offsets). Base = 118,407,168 B (proven). Optional
// XH2 (fp16 x row-major) appended if ws_size >= 168,738,816.
// ---------------------------------------------------------------------------
static const size_t XT_B   = 0;           // fp16 x^T [b][c][n]; dies after G
static const size_t UT_B   = 0;           // overlays XT
static const size_t ATT_B  = 28311552;
static const size_t MT_B   = 29491200;
static const size_t PT_B   = 38928384;
static const size_t GP_B   = 50331648;    // G partials; dies after reduce
static const size_t XH_B   = 50331648;    // fallback XH (fills after reduce)
static const size_t WH_B   = 100663296;
static const size_t WT_B   = 104202240;
static const size_t WPT_B  = 107741184;
static const size_t G_B    = 108920832;
static const size_t INV_B  = 118358016;
static const size_t XH2_B  = 118407168;   // fast-path XH (needs big ws)
static const size_t XH_BYTES = (size_t)NB * SEQ * CH * 2;   // 50,331,648

// ---------------------------------------------------------------------------
// async global->LDS, 16 B per lane (wave-uniform LDS base + lane*16)
// ---------------------------------------------------------------------------
__device__ __forceinline__ void gload16(const void* g, void* l) {
  __builtin_amdgcn_global_load_lds(
      (const __attribute__((address_space(1))) void*)g,
      (__attribute__((address_space(3))) void*)l, 16, 0, 0);
}

// ---------------------------------------------------------------------------
// Elementwise fp32 -> fp16 convert (fallback XH path only)
// ---------------------------------------------------------------------------
__global__ void cvt_f16_kernel(const float* __restrict__ in,
                               _Float16* __restrict__ out, int n4) {
  int i = blockIdx.x * blockDim.x + threadIdx.x;
  if (i < n4) {
    float4 v = *(const float4*)(in + (size_t)i * 4);
    _Float16* o = out + (size_t)i * 4;
    o[0] = (_Float16)v.x; o[1] = (_Float16)v.y;
    o[2] = (_Float16)v.z; o[3] = (_Float16)v.w;
  }
}

// ---------------------------------------------------------------------------
// Vectorized 64x64 transpose+convert: fp32 [R][C] -> fp16 [C][R] (outT, 16B
// stores via LDS), optional fp16 [R][C] (outH, 8B stores). grid (C/64, R/64,
// batch), 256 threads. Load: float4; LDS [64][68] f32 (16B-aligned rows).
// ---------------------------------------------------------------------------
__global__ __launch_bounds__(256) void transpose64_kernel(
    const float* __restrict__ in, _Float16* __restrict__ outT,
    _Float16* __restrict__ outH, int R, int C, long sIn, long sOut) {
  __shared__ __align__(16) float ts[64][68];
  const int b = blockIdx.z;
  const int c0 = blockIdx.x * 64, r0 = blockIdx.y * 64;
  const float* ib = in + (size_t)b * sIn;

  const int c4 = (threadIdx.x & 15) * 4;      // col within tile, x4
  const int rr = threadIdx.x >> 4;            // 0..15
#pragma unroll
  for (int q = 0; q < 4; ++q) {
    const int row = rr + 16 * q;
    float4 v = *(const float4*)&ib[(size_t)(r0 + row) * C + c0 + c4];
    *(float4*)&ts[row][c4] = v;
    if (outH) {
      f16x4 h = {(_Float16)v.x, (_Float16)v.y, (_Float16)v.z, (_Float16)v.w};
      *(f16x4*)&outH[(size_t)b * sOut + (size_t)(r0 + row) * C + c0 + c4] = h;
    }
  }
  __syncthreads();

  // transposed write: thread covers col (t>>2), 16 n at nseg=(t&3)*16
  const int col = threadIdx.x >> 2;
  const int nseg = (threadIdx.x & 3) * 16;
  _Float16* ob = outT + (size_t)b * sOut + (size_t)(c0 + col) * R + r0 + nseg;
#pragma unroll
  for (int half = 0; half < 2; ++half) {
    f16x8 h;
#pragma unroll
    for (int j = 0; j < 8; ++j)
      h[j] = (_Float16)ts[nseg + half * 8 + j][col];
    *(f16x8*)&ob[half * 8] = h;
  }
}

// ---------------------------------------------------------------------------
// 128x128 4-wave MFMA GEMM, BK=32 — depth-3 counted-vmcnt pipeline (r10).
// Direct-store epilogue (r11's LDS repack caused 393K bank conflicts; reverted).
// TRI: upper-tri 6x6 128-tiling for symmetric output. nwg%8==0.
// ---------------------------------------------------------------------------
template<bool FP16OUT, bool BIAS, bool TRI>
__global__ __launch_bounds__(256) void gemm_bt_mfma(
    const _Float16* __restrict__ Ap, const _Float16* __restrict__ Bp,
    const float* __restrict__ bias, void* __restrict__ Cp,
    int K, int lda, int ldb, int ldc,
    long sA, long sB, long sC, int zdiv, long aCS, long bCS, long cCS,
    int gx, int gy) {
  __shared__ __align__(16) _Float16 ldsA[3][128 * 32];
  __shared__ __align__(16) _Float16 ldsB[3][128 * 32];

  const int nwg = gridDim.x;
  const int lid = blockIdx.x;
  const int wg = (lid & 7) * (nwg >> 3) + (lid >> 3);
  int bx, by, z;
  if constexpr (TRI) {
    int tt = wg % 21; z = wg / 21;
    int ti = 0, rem = tt;
    while (rem >= 6 - ti) { rem -= 6 - ti; ++ti; }
    by = ti; bx = ti + rem;
  } else {
    bx = wg % gx; int r2 = wg / gx; by = r2 % gy; z = r2 / gy;
  }
  const int bat = z % zdiv, chk = z / zdiv;
  const _Float16* A = Ap + (size_t)bat * sA + (size_t)chk * aCS;
  const _Float16* B = Bp + (size_t)bat * sB + (size_t)chk * bCS;
  const size_t cOff = (size_t)bat * sC + (size_t)chk * cCS;

  const int row0 = by * 128, col0 = bx * 128;
  const int tid = threadIdx.x;
  const int l = tid & 63, w = tid >> 6;
  const int lo = l & 15, hi = l >> 4;
  const int wr = w >> 1, wc = w & 1;
  const int rw = 32 * w;
  const int lr = l >> 2;
  const int ls = l & 3;

  f32x4 acc[4][4];
#pragma unroll
  for (int i = 0; i < 4; ++i)
#pragma unroll
    for (int j = 0; j < 4; ++j)
      acc[i][j] = (f32x4){0.f, 0.f, 0.f, 0.f};

  auto STAGE = [&](int hb, int k0) {
#pragma unroll
    for (int q = 0; q < 2; ++q) {
      const int r = rw + 16 * q + lr;
      const int ck = ls ^ ((r >> 1) & 3);
      gload16(A + (size_t)(row0 + r) * lda + k0 + 8 * ck,
              &ldsA[hb][(rw + 16 * q) * 32]);
      gload16(B + (size_t)(col0 + r) * ldb + k0 + 8 * ck,
              &ldsB[hb][(rw + 16 * q) * 32]);
    }
  };

  const int nt = K / 32;
  STAGE(0, 0);
  if (nt > 1) STAGE(1, 32);
  int cur = 0;
  for (int t = 0; t < nt; ++t) {
    if (t + 2 < nt) {
      int n2 = cur + 2; if (n2 >= 3) n2 -= 3;
      STAGE(n2, 32 * (t + 2));
      asm volatile("s_waitcnt vmcnt(8)" ::: "memory");   // tile t done
    } else if (t + 1 < nt) {
      asm volatile("s_waitcnt vmcnt(4)" ::: "memory");
    } else {
      asm volatile("s_waitcnt vmcnt(0)" ::: "memory");
    }
    __builtin_amdgcn_s_barrier();

    f16x8 a[4], b[4];
#pragma unroll
    for (int mi = 0; mi < 4; ++mi) {
      int Ra = 64 * wr + 16 * mi + lo;
      a[mi] = *(const f16x8*)&ldsA[cur][Ra * 32 + (hi ^ ((Ra >> 1) & 3)) * 8];
    }
#pragma unroll
    for (int ni = 0; ni < 4; ++ni) {
      int Rb = 64 * wc + 16 * ni + lo;
      b[ni] = *(const f16x8*)&ldsB[cur][Rb * 32 + (hi ^ ((Rb >> 1) & 3)) * 8];
    }
#pragma unroll
    for (int mi = 0; mi < 4; ++mi)
#pragma unroll
      for (int ni = 0; ni < 4; ++ni)
        acc[mi][ni] = __builtin_amdgcn_mfma_f32_16x16x32_f16(
            a[mi], b[ni], acc[mi][ni], 0, 0, 0);

    __builtin_amdgcn_s_barrier();   // all reads of buf cur done
    ++cur; if (cur == 3) cur = 0;
  }

#pragma unroll
  for (int ni = 0; ni < 4; ++ni) {
    const int col = col0 + 64 * wc + 16 * ni + lo;
    float bv = 0.f;
    if constexpr (BIAS) bv = bias[col];
#pragma unroll
    for (int mi = 0; mi < 4; ++mi) {
      const int rowb = row0 + 64 * wr + 16 * mi + 4 * hi;
#pragma unroll
      for (int r = 0; r < 4; ++r) {
        float v = acc[mi][ni][r] + bv;
        if constexpr (FP16OUT)
          ((_Float16*)Cp)[cOff + (size_t)(rowb + r) * ldc + col] = (_Float16)v;
        else
          ((float*)Cp)[cOff + (size_t)(rowb + r) * ldc + col] = v;
      }
    }
  }
}

// ---------------------------------------------------------------------------
// Reduce 4 split-K chunks of the 21 upper-tri 128-tiles and mirror to full G.
// grid (21, 8), block 256.
// ---------------------------------------------------------------------------
__global__ void reduce_mirror_kernel(const _Float16* __restrict__ GP,
                                     _Float16* __restrict__ G) {
  const int t = blockIdx.x, b = blockIdx.y;
  int ti = 0, rem = t;
  while (rem >= 6 - ti) { rem -= 6 - ti; ++ti; }
  const int tj = ti + rem;
  const int i0 = ti * 128, j0 = tj * 128;
  const int tx = threadIdx.x & 31, ty = threadIdx.x >> 5;
  __shared__ float lds[32][33];
  const size_t cs = (size_t)NB * CH * CH;
  const _Float16* gp = GP + (size_t)b * CH * CH;
  _Float16* g = G + (size_t)b * CH * CH;

  for (int st = 0; st < 16; ++st) {
    const int sr = i0 + (st >> 2) * 32, sc = j0 + (st & 3) * 32;
    __syncthreads();
#pragma unroll
    for (int k = 0; k < 4; ++k) {
      const int r = ty + 8 * k;
      const size_t off = (size_t)(sr + r) * CH + sc + tx;
      float v = ((float)gp[off] + (float)gp[cs + off]) +
                ((float)gp[2 * cs + off] + (float)gp[3 * cs + off]);
      lds[r][tx] = v;
      g[off] = (_Float16)v;
    }
    if (ti != tj) {
      __syncthreads();
#pragma unroll
      for (int k = 0; k < 4; ++k) {
        const int r = ty + 8 * k;
        g[(size_t)(sc + r) * CH + sr + tx] = (_Float16)lds[tx][r];
      }
    }
  }
}

// ---------------------------------------------------------------------------
// Norms: INV[t*8+b][c] = 1/max(sqrt(sum_i Ut[t][b][c][i]*Wt[t*768+c][i]),eps)
// ---------------------------------------------------------------------------
__global__ void norm_kernel(const _Float16* __restrict__ Ut,
                            const _Float16* __restrict__ Wt,
                            float* __restrict__ INVv) {
  const int z = blockIdx.x;
  const int t = z >> 3;
  const int c = blockIdx.y * 128 + threadIdx.x;
  const _Float16* u = Ut + ((size_t)z * CH + c) * CH;
  const _Float16* wv = Wt + ((size_t)(t * CH + c)) * CH;
  float s = 0.f;
  for (int i = 0; i < CH; i += 8) {
    f16x8 uv = *(const f16x8*)(u + i);
    f16x8 wq = *(const f16x8*)(wv + i);
#pragma unroll
    for (int q = 0; q < 8; ++q) s += (float)uv[q] * (float)wq[q];
  }
  s = fmaxf(s, 0.f);
  INVv[(size_t)z * CH + c] = 1.0f / fmaxf(sqrtf(s), 1e-12f);
}

// ---------------------------------------------------------------------------
// Fused S = Wq-rows . Ut1-rows^T (96x96, K=768) via MFMA, scale, softmax
// over e, transposed fp16 ATt write. grid 64 (bh), 256 threads.
// ---------------------------------------------------------------------------
__global__ __launch_bounds__(256) void sattn_kernel(
    const _Float16* __restrict__ WT_, const _Float16* __restrict__ UT_,
    const float* __restrict__ INVv, const float* __restrict__ temp,
    _Float16* __restrict__ ATt) {
  const int bh = blockIdx.x;
  const int b = bh >> 3, h = bh & 7;
  __shared__ __align__(16) _Float16 lds[2][192 * 32];
  __shared__ float S[96][100];

  const int tid = threadIdx.x;
  const int l = tid & 63, w = tid >> 6;
  const int lo = l & 15, hi = l >> 4;
  const int wr = w >> 1, wc = w & 1;
  const int lr = l >> 2, lq = l & 3;

  const _Float16* Abase = WT_ + (size_t)(h * HD) * CH;
  const _Float16* Bbase = UT_ + ((size_t)(8 + b) * CH + h * HD) * CH;

  f32x4 acc[3][3];
#pragma unroll
  for (int i = 0; i < 3; ++i)
#pragma unroll
    for (int j = 0; j < 3; ++j)
      acc[i][j] = (f32x4){0.f, 0.f, 0.f, 0.f};

  auto STAGE = [&](int hb, int k0) {
#pragma unroll
    for (int c = 0; c < 3; ++c) {
      const int group = w * 3 + c;
      const int row = group * 16 + lr;
      const int ck = lq ^ ((row >> 1) & 3);
      const _Float16* src = (row < 96)
          ? Abase + (size_t)row * CH + k0 + 8 * ck
          : Bbase + (size_t)(row - 96) * CH + k0 + 8 * ck;
      gload16(src, &lds[hb][group * 512]);
    }
  };

  STAGE(0, 0);
  int cur = 0;
  for (int t = 0; t < 24; ++t) {
    if (t + 1 < 24) {
      STAGE(cur ^ 1, 32 * (t + 1));
      asm volatile("s_waitcnt vmcnt(3)" ::: "memory");
    } else {
      asm volatile("s_waitcnt vmcnt(0)" ::: "memory");
    }
    __builtin_amdgcn_s_barrier();

    f16x8 a[3], bb[3];
#pragma unroll
    for (int mi = 0; mi < 3; ++mi) {
      const int Ra = 48 * wr + 16 * mi + lo;
      a[mi] = *(const f16x8*)&lds[cur][Ra * 32 + (hi ^ ((Ra >> 1) & 3)) * 8];
    }
#pragma unroll
    for (int ni = 0; ni < 3; ++ni) {
      const int Rb = 96 + 48 * wc + 16 * ni + lo;
      bb[ni] = *(const f16x8*)&lds[cur][Rb * 32 + (hi ^ ((Rb >> 1) & 3)) * 8];
    }
#pragma unroll
    for (int mi = 0; mi < 3; ++mi)
#pragma unroll
      for (int ni = 0; ni < 3; ++ni)
        acc[mi][ni] = __builtin_amdgcn_mfma_f32_16x16x32_f16(
            a[mi], bb[ni], acc[mi][ni], 0, 0, 0);

    __builtin_amdgcn_s_barrier();
    cur ^= 1;
  }

  const float tv = temp[h];
  const float* iq = INVv + (size_t)b * CH + h * HD;
  const float* ik = INVv + (size_t)(8 + b) * CH + h * HD;
#pragma unroll
  for (int ni = 0; ni < 3; ++ni) {
    const int col = 48 * wc + 16 * ni + lo;
    const float ikv = ik[col];
#pragma unroll
    for (int mi = 0; mi < 3; ++mi) {
      const int rb = 48 * wr + 16 * mi + 4 * hi;
#pragma unroll
      for (int r = 0; r < 4; ++r)
        S[rb + r][col] = acc[mi][ni][r] * iq[rb + r] * ikv * tv;
    }
  }
  __syncthreads();

  const int g16 = tid >> 4, l16 = tid & 15;
  _Float16* ab = ATt + (size_t)bh * 9216;
#pragma unroll
  for (int it = 0; it < 6; ++it) {
    const int d = g16 + 16 * it;
    float v[6];
    float mx = -INFINITY;
#pragma unroll
    for (int j = 0; j < 6; ++j) { v[j] = S[d][l16 * 6 + j]; mx = fmaxf(mx, v[j]); }
#pragma unroll
    for (int m = 1; m < 16; m <<= 1) mx = fmaxf(mx, __shfl_xor(mx, m, 16));
    float sum = 0.f;
#pragma unroll
    for (int j = 0; j < 6; ++j) { v[j] = __expf(v[j] - mx); sum += v[j]; }
#pragma unroll
    for (int m = 1; m < 16; m <<= 1) sum += __shfl_xor(sum, m, 16);
    const float inv = 1.0f / sum;
#pragma unroll
    for (int j = 0; j < 6; ++j)
      ab[(size_t)(l16 * 6 + j) * 96 + d] = (_Float16)(v[j] * inv);
  }
}

// ---------------------------------------------------------------------------
// Mt[b][j][h*96+e] = sum_d Wpt[j][h96+d] * ATt[bh][e][d]
// ---------------------------------------------------------------------------
__global__ void mt_kernel(const _Float16* __restrict__ Wpt,
                          const _Float16* __restrict__ ATt,
                          _Float16* __restrict__ Mt) {
  const int j0 = blockIdx.x * 128;
  const int bh = blockIdx.y;
  const int b = bh >> 3, h = bh & 7;
  const int tx = threadIdx.x & 15, ty = threadIdx.x >> 4;
  __shared__ float Ws[16][128], Ats[16][96];
  float acc[8][6] = {};

  for (int d0 = 0; d0 < 96; d0 += 16) {
    {
      int jj = threadIdx.x >> 1, s8 = (threadIdx.x & 1) * 8;
      f16x8 v = *(const f16x8*)(Wpt + (size_t)(j0 + jj) * CH + h * HD + d0 + s8);
#pragma unroll
      for (int q = 0; q < 8; ++q) Ws[s8 + q][jj] = (float)v[q];
    }
    if (threadIdx.x < 192) {
      int e = threadIdx.x >> 1, s8 = (threadIdx.x & 1) * 8;
      f16x8 v = *(const f16x8*)(ATt + (size_t)bh * 9216 + (size_t)e * 96 + d0 + s8);
#pragma unroll
      for (int q = 0; q < 8; ++q) Ats[s8 + q][e] = (float)v[q];
    }
    __syncthreads();
#pragma unroll
    for (int kk = 0; kk < 16; ++kk) {
      float a[8], bb[6];
#pragma unroll
      for (int i = 0; i < 8; ++i) a[i] = Ws[kk][ty * 8 + i];
#pragma unroll
      for (int j = 0; j < 6; ++j) bb[j] = Ats[kk][tx * 6 + j];
#pragma unroll
      for (int i = 0; i < 8; ++i)
#pragma unroll
        for (int j = 0; j < 6; ++j)
          acc[i][j] += a[i] * bb[j];
    }
    __syncthreads();
  }

  _Float16* mb = Mt + (size_t)b * CH * CH;
#pragma unroll
  for (int i = 0; i < 8; ++i)
#pragma unroll
    for (int j = 0; j < 6; ++j)
      mb[(size_t)(j0 + ty * 8 + i) * CH + h * HD + tx * 6 + j] = (_Float16)acc[i][j];
}

// ---------------------------------------------------------------------------
extern "C" void kernel_launch(void* const* d_in, const int* in_sizes, int n_in,
                              void* d_out, int out_size, void* d_ws, size_t ws_size,
                              hipStream_t stream) {
  const float* x      = (const float*)d_in[0];
  const float* W_qkv  = (const float*)d_in[1];
  const float* W_proj = (const float*)d_in[2];
  const float* b_proj = (const float*)d_in[3];
  const float* temp   = (const float*)d_in[4];
  float* out = (float*)d_out;
  char* ws = (char*)d_ws;

  _Float16* XT  = (_Float16*)(ws + XT_B);
  _Float16* UT  = (_Float16*)(ws + UT_B);
  _Float16* ATT = (_Float16*)(ws + ATT_B);
  _Float16* MT  = (_Float16*)(ws + MT_B);
  _Float16* PT  = (_Float16*)(ws + PT_B);
  _Float16* GP  = (_Float16*)(ws + GP_B);
  _Float16* XH  = (_Float16*)(ws + XH_B);
  _Float16* WH  = (_Float16*)(ws + WH_B);
  _Float16* WT  = (_Float16*)(ws + WT_B);
  _Float16* WPT = (_Float16*)(ws + WPT_B);
  _Float16* G   = (_Float16*)(ws + G_B);
  float*    INV = (float*)   (ws + INV_B);

  const bool fast = ws_size >= XH2_B + XH_BYTES;   // 168.7 MB
  _Float16* XHU = fast ? (_Float16*)(ws + XH2_B) : XH;

  const long CC = (long)CH * CH;           // 589824
  const long SC = (long)SEQ * CH;          // 3145728

  // --- transposes (vectorized); WH fused into the WT pass ---
  transpose64_kernel<<<dim3(CH / 64, SEQ / 64, NB), 256, 0, stream>>>(
      x, XT, fast ? XHU : nullptr, SEQ, CH, SC, SC);
  transpose64_kernel<<<dim3(NC3 / 64, CH / 64, 1), 256, 0, stream>>>(
      W_qkv, WT, WH, CH, NC3, 0, 0);
  transpose64_kernel<<<dim3(CH / 64, CH / 64, 1), 256, 0, stream>>>(
      W_proj, WPT, nullptr, CH, CH, 0, 0);

  // --- G upper-tri partials: 21 tiles x (8 b x 4 K-chunks) = 672 blocks ---
  gemm_bt_mfma<true, false, true><<<672, 256, 0, stream>>>(
      XT, XT, nullptr, GP, 1024, SEQ, SEQ, CH,
      (long)CH * SEQ, (long)CH * SEQ, CC, NB, 1024, 1024, (long)NB * CC,
      21, 1);

  // --- reduce chunks + mirror to full symmetric G ---
  reduce_mirror_kernel<<<dim3(21, NB), 256, 0, stream>>>(GP, G);

  // --- U fused over t: UT[t][b] = Wt_t . G_b^T  (z = t*8+b), 576 blocks ---
  gemm_bt_mfma<true, false, false><<<576, 256, 0, stream>>>(
      WT, G, nullptr, UT, CH, CH, CH, CH,
      0, CC, CC, NB, CC, 0, (long)NB * CC, 6, 6);

  // --- norms ---
  norm_kernel<<<dim3(16, 6), 128, 0, stream>>>(UT, WT, INV);

  // --- fused S + scale + softmax -> ATt ---
  sattn_kernel<<<64, 256, 0, stream>>>(WT, UT, INV, temp, ATT);

  // --- Mt ---
  mt_kernel<<<dim3(6, 64), 256, 0, stream>>>(WPT, ATT, MT);

  // --- Pt_b = Mt_b . Wv^T (288 blocks) ---
  gemm_bt_mfma<true, false, false><<<288, 256, 0, stream>>>(
      MT, WH + 2 * CH, nullptr, PT, CH, CH, NC3, CH,
      CC, 0, CC, NB, 0, 0, 0, 6, 6);

  // --- fallback: x -> XH (GP dead after reduce_mirror) ---
  if (!fast)
    cvt_f16_kernel<<<(int)(NB * SC / 4 / 256), 256, 0, stream>>>(
        x, XH, (int)(NB * SC / 4));

  // --- out_b = XH_b . Pt_b^T + bias  (M=4096, N=768, K=768), 1536 blocks ---
  gemm_bt_mfma<false, true, false><<<1536, 256, 0, stream>>>(
      XHU, PT, b_proj, out, CH, CH, CH, CH,
      SC, CC, SC, NB, 0, 0, 0, 6, 32);
}